// Round 12
// baseline (352.788 us; speedup 1.0000x reference)
//
#include <hip/hip_runtime.h>

typedef __bf16 bf16_t;
typedef __bf16 bf16x8 __attribute__((ext_vector_type(8)));
typedef float  f32x4  __attribute__((ext_vector_type(4)));

#define NB    64
#define EB    4032            // NB*(NB-1)
#define BATCH 32
#define H     256
#define M_EDGE (BATCH*EB)     // 129024
#define M_NODE (BATCH*NB)     // 2048
#define BN_EPS 1e-5f

__device__ __forceinline__ void load_lds16(const void* g, void* l) {
    __builtin_amdgcn_global_load_lds(
        (const __attribute__((address_space(1))) unsigned int*)g,
        (__attribute__((address_space(3))) unsigned int*)l, 16, 0, 0);
}
// fast ELU: v_exp_f32 (+mul) instead of ~35-inst expm1f; bf16-rounding dwarfs the error
__device__ __forceinline__ float elu(float v) { return v > 0.f ? v : __expf(v) - 1.f; }

// ---------------------------------------------------------------------------
// Fused 2-layer node MLP, STREAMED-B (R9 winner): W1/W2 pre-permuted to
// FRAGMENT ORDER (prep groups 0,1,3,4); 5 barriers; numerics identical.
// ---------------------------------------------------------------------------
template<bool AF32>
__global__ __launch_bounds__(256, 3)
void fused_mlp(const void* __restrict__ A0v,
               const bf16_t* __restrict__ W1f, const float* __restrict__ b1,
               const bf16_t* __restrict__ W2f, const float* __restrict__ b2,
               bf16_t* __restrict__ out, float* __restrict__ stats)
{
    const int m0 = blockIdx.x * 64;
    const int tid = threadIdx.x, wave = tid >> 6, lane = tid & 63;
    const int l15 = lane & 15, quad = lane >> 4;
    const int row = tid >> 2;
    const int c0 = (tid & 3) * 64;

    __shared__ bf16_t h1s[64 * 264];
    __shared__ float  sred[512];

    sred[tid] = 0.f; sred[256 + tid] = 0.f;

    // stage A tile (64x256) into padded LDS
    if (AF32) {
        const float* af = (const float*)A0v + (size_t)(m0 + row) * 256 + c0;
#pragma unroll
        for (int j = 0; j < 8; ++j) {
            float4 lo = *(const float4*)(af + j * 8);
            float4 hi = *(const float4*)(af + j * 8 + 4);
            bf16x8 v;
            v[0]=(bf16_t)lo.x; v[1]=(bf16_t)lo.y; v[2]=(bf16_t)lo.z; v[3]=(bf16_t)lo.w;
            v[4]=(bf16_t)hi.x; v[5]=(bf16_t)hi.y; v[6]=(bf16_t)hi.z; v[7]=(bf16_t)hi.w;
            *(bf16x8*)&h1s[row * 264 + c0 + j * 8] = v;
        }
    } else {
        const bf16_t* src = (const bf16_t*)A0v + (size_t)(m0 + row) * 256 + c0;
#pragma unroll
        for (int j = 0; j < 8; ++j)
            *(bf16x8*)&h1s[row * 264 + c0 + j * 8] = *(const bf16x8*)(src + j * 8);
    }

    // per-wave fragment-order bases
    const bf16_t* W1W = W1f + (size_t)wave * 16384;
    const bf16_t* W2W = W2f + (size_t)wave * 16384;

    bf16x8 bcur[4], bnxt[4];
#pragma unroll
    for (int u = 0; u < 4; ++u)
        bcur[u] = *(const bf16x8*)(W1W + u * 512 + lane * 8);
    __syncthreads();                     // A tile ready (B ks=0 in flight)

    f32x4 acc[4][4];
#pragma unroll
    for (int a = 0; a < 4; ++a)
#pragma unroll
        for (int u = 0; u < 4; ++u) acc[a][u] = (f32x4){0.f, 0.f, 0.f, 0.f};

    // ---- layer 1: A @ W1 (streamed B, barrier-free) ----
#pragma unroll
    for (int ks = 0; ks < 8; ++ks) {
        if (ks < 7) {
#pragma unroll
            for (int u = 0; u < 4; ++u)
                bnxt[u] = *(const bf16x8*)(W1W + (ks + 1) * 2048 + u * 512 + lane * 8);
        }
        bf16x8 afr[4];
#pragma unroll
        for (int a = 0; a < 4; ++a)
            afr[a] = *(const bf16x8*)&h1s[(a * 16 + l15) * 264 + ks * 32 + quad * 8];
#pragma unroll
        for (int a = 0; a < 4; ++a)
#pragma unroll
            for (int u = 0; u < 4; ++u)
                acc[a][u] = __builtin_amdgcn_mfma_f32_16x16x32_bf16(afr[a], bcur[u], acc[a][u], 0, 0, 0);
#pragma unroll
        for (int u = 0; u < 4; ++u) bcur[u] = bnxt[u];
    }

    // prefetch layer-2 ks=0 (hides under h1 spill)
#pragma unroll
    for (int u = 0; u < 4; ++u)
        bcur[u] = *(const bf16x8*)(W2W + u * 512 + lane * 8);
    __syncthreads();                     // B1: all layer-1 LDS reads done

    // h1 = ELU(acc + b1), spilled to LDS row-major
#pragma unroll
    for (int u = 0; u < 4; ++u) {
        int   col = wave * 64 + u * 16 + l15;
        float bv  = b1[col];
#pragma unroll
        for (int a = 0; a < 4; ++a)
#pragma unroll
            for (int r = 0; r < 4; ++r)
                h1s[(a * 16 + quad * 4 + r) * 264 + col] = (bf16_t)elu(acc[a][u][r] + bv);
    }
    __syncthreads();                     // B2: h1 visible

    // ---- layer 2: h1 @ W2 (streamed B, barrier-free) ----
#pragma unroll
    for (int a = 0; a < 4; ++a)
#pragma unroll
        for (int u = 0; u < 4; ++u) acc[a][u] = (f32x4){0.f, 0.f, 0.f, 0.f};
#pragma unroll
    for (int ks = 0; ks < 8; ++ks) {
        if (ks < 7) {
#pragma unroll
            for (int u = 0; u < 4; ++u)
                bnxt[u] = *(const bf16x8*)(W2W + (ks + 1) * 2048 + u * 512 + lane * 8);
        }
        bf16x8 afr[4];
#pragma unroll
        for (int a = 0; a < 4; ++a)
            afr[a] = *(const bf16x8*)&h1s[(a * 16 + l15) * 264 + ks * 32 + quad * 8];
#pragma unroll
        for (int a = 0; a < 4; ++a)
#pragma unroll
            for (int u = 0; u < 4; ++u)
                acc[a][u] = __builtin_amdgcn_mfma_f32_16x16x32_bf16(afr[a], bcur[u], acc[a][u], 0, 0, 0);
#pragma unroll
        for (int u = 0; u < 4; ++u) bcur[u] = bnxt[u];
    }
    __syncthreads();                     // B3: all layer-2 LDS reads done

    // epilogue: ELU + BN stats + bf16 write-back
#pragma unroll
    for (int u = 0; u < 4; ++u) {
        int   col = wave * 64 + u * 16 + l15;
        float bv  = b2[col];
        float s = 0.f, q = 0.f;
#pragma unroll
        for (int a = 0; a < 4; ++a)
#pragma unroll
            for (int r = 0; r < 4; ++r) {
                float v = elu(acc[a][u][r] + bv);
                h1s[(a * 16 + quad * 4 + r) * 264 + col] = (bf16_t)v;
                s += v; q += v * v;
            }
        s += __shfl_xor(s, 16); s += __shfl_xor(s, 32);
        q += __shfl_xor(q, 16); q += __shfl_xor(q, 32);
        if (quad == 0) { atomicAdd(&sred[col], s); atomicAdd(&sred[256 + col], q); }
    }
    __syncthreads();                     // B4: outputs staged

#pragma unroll
    for (int p = 0; p < 8; ++p) {
        int idx = p * 256 + tid;
        int r = idx >> 5, ch = idx & 31;
        *(uint4*)&out[(size_t)(m0 + r) * H + ch * 8] = *(const uint4*)&h1s[r * 264 + ch * 8];
    }
    atomicAdd(&stats[tid],     sred[tid]);
    atomicAdd(&stats[H + tid], sred[256 + tid]);
}

// ---------------------------------------------------------------------------
// Node GEMM w/ BN fold on A (sc computed in-kernel from raw stats):
// out[M,512] = (A*scale+shift)[M,256] @ Wt^T + bias.
// ---------------------------------------------------------------------------
__global__ __launch_bounds__(256)
void node_gemm(const bf16_t* __restrict__ A, const float* __restrict__ statsIn,
               const float* __restrict__ g, const float* __restrict__ beta, float Mcnt,
               const bf16_t* __restrict__ Wt, const float* __restrict__ bias,
               float* __restrict__ out)
{
    const int m0 = blockIdx.x * 64;
    const int nb = blockIdx.y * 256;
    const int tid = threadIdx.x, wave = tid >> 6, lane = tid & 63;
    const int l15 = lane & 15, quad = lane >> 4;
    const int row = tid >> 2;
    const int cx8 = (((tid & 3) ^ ((tid >> 3) & 3))) * 8;
    const int sl8 = (tid & 3) * 8;
    const int xq8 = (quad ^ ((l15 >> 1) & 3)) * 8;
    __shared__ bf16_t As[64 * 32];
    __shared__ bf16_t Bs[256 * 32];
    __shared__ float  ss[512];   // scale | shift

    {   // BN finalize inline (replaces bn_finalize dispatch)
        float mean = statsIn[tid] / Mcnt;
        float var  = statsIn[256 + tid] / Mcnt - mean * mean;
        float scl  = g[tid] * rsqrtf(var + BN_EPS);
        ss[tid]       = scl;
        ss[256 + tid] = beta[tid] - mean * scl;
    }
    __syncthreads();

    f32x4 acc[4][4];
#pragma unroll
    for (int t = 0; t < 4; ++t)
#pragma unroll
        for (int u = 0; u < 4; ++u) acc[t][u] = (f32x4){0.f, 0.f, 0.f, 0.f};

    for (int k0 = 0; k0 < 256; k0 += 32) {
        {   // BN-folded A staging (VGPR path)
            int kc = k0 + cx8;
            bf16x8 v = *(const bf16x8*)(A + (size_t)(m0 + row) * 256 + kc);
            bf16x8 w;
#pragma unroll
            for (int j = 0; j < 8; ++j)
                w[j] = (bf16_t)((float)v[j] * ss[kc + j] + ss[256 + kc + j]);
            *(bf16x8*)&As[row * 32 + sl8] = w;
        }
#pragma unroll
        for (int p = 0; p < 4; ++p)
            load_lds16(Wt + (size_t)(nb + p * 64 + row) * 256 + k0 + cx8,
                       Bs + (p * 256 + wave * 64) * 8);
        __syncthreads();
        bf16x8 afr[4], bfr[4];
#pragma unroll
        for (int t = 0; t < 4; ++t)
            afr[t] = *(const bf16x8*)&As[(t * 16 + l15) * 32 + xq8];
#pragma unroll
        for (int u = 0; u < 4; ++u)
            bfr[u] = *(const bf16x8*)&Bs[(wave * 64 + u * 16 + l15) * 32 + xq8];
#pragma unroll
        for (int t = 0; t < 4; ++t)
#pragma unroll
            for (int u = 0; u < 4; ++u)
                acc[t][u] = __builtin_amdgcn_mfma_f32_16x16x32_bf16(afr[t], bfr[u], acc[t][u], 0, 0, 0);
        __syncthreads();
    }
#pragma unroll
    for (int u = 0; u < 4; ++u) {
        int col = nb + wave * 64 + u * 16 + l15;
        float bv = bias[col];
#pragma unroll
        for (int t = 0; t < 4; ++t)
#pragma unroll
            for (int r = 0; r < 4; ++r)
                out[(size_t)(m0 + t * 16 + quad * 4 + r) * 512 + col] = acc[t][u][r] + bv;
    }
}

// ---------------------------------------------------------------------------
// MLP2 (R12): m4-R11 structure applied to the edge MLP's single GEMM.
// Streamed fragment-order W2b (prep grp 2 now fragment-order), computeA
// writes ELU(P+Q) straight into the XOR-swizzled chunk layout (8x[64][32]),
// block-uniform edge decomposition, T=1, grid 2016, 3 barriers/block.
// Numerics identical to the Breg form (same f32 adds/ELU/rounding/ks order).
// ---------------------------------------------------------------------------
__global__ __launch_bounds__(256, 3)
void m2_kernel(const float* __restrict__ PQ, const bf16_t* __restrict__ W2f,
               const float* __restrict__ b2, bf16_t* __restrict__ out,
               float* __restrict__ stats)
{
    const int m0 = blockIdx.x * 64;
    const int tid = threadIdx.x, wave = tid >> 6, lane = tid & 63;
    const int l15 = lane & 15, quad = lane >> 4;
    const int row = tid >> 2;
    const int c0 = (tid & 3) * 64;
    const int xq8 = (quad ^ ((l15 >> 1) & 3)) * 8;

    __shared__ bf16_t h1s[8 * 2048];     // 8 ks-chunks x [64 rows][32 cols], swizzled
    __shared__ float  sred[512];

    sred[tid] = 0.f; sred[256 + tid] = 0.f;

    // block-uniform edge decomposition (SALU)
    const int bb  = m0 / EB;
    const int e0  = m0 - bb * EB;
    const int sn0 = e0 / (NB - 1);
    const int rr0 = e0 - sn0 * (NB - 1);

    // computeA: ELU(P+Q) for this thread's 64 cols of row `row`, written
    // directly into the swizzled chunk layout
    {
        int t  = rr0 + row;
        int wrap = (t >= NB - 1) ? 1 : 0;
        int sn = sn0 + wrap;
        int rr = t - (wrap ? (NB - 1) : 0);
        int rc = rr + (rr >= sn ? 1 : 0);
        const float* Prow = PQ + (size_t)(bb * NB + sn) * 512;
        const float* Qrow = PQ + (size_t)(bb * NB + rc) * 512 + 256;
        const int rs = ((row >> 1) & 3);
#pragma unroll
        for (int j = 0; j < 8; ++j) {
            int c = c0 + j * 8;
            float4 p0 = *(const float4*)(Prow + c);
            float4 p1 = *(const float4*)(Prow + c + 4);
            float4 q0 = *(const float4*)(Qrow + c);
            float4 q1 = *(const float4*)(Qrow + c + 4);
            bf16x8 v;
            v[0]=(bf16_t)elu(p0.x+q0.x); v[1]=(bf16_t)elu(p0.y+q0.y);
            v[2]=(bf16_t)elu(p0.z+q0.z); v[3]=(bf16_t)elu(p0.w+q0.w);
            v[4]=(bf16_t)elu(p1.x+q1.x); v[5]=(bf16_t)elu(p1.y+q1.y);
            v[6]=(bf16_t)elu(p1.z+q1.z); v[7]=(bf16_t)elu(p1.w+q1.w);
            *(bf16x8*)&h1s[(c >> 5) * 2048 + row * 32 + ((((c >> 3) & 3) ^ rs) * 8)] = v;
        }
    }

    // stream B ks=0 (in flight across the barrier)
    const bf16_t* W2W = W2f + (size_t)wave * 16384;
    bf16x8 bcur[4], bnxt[4];
#pragma unroll
    for (int u = 0; u < 4; ++u)
        bcur[u] = *(const bf16x8*)(W2W + u * 512 + lane * 8);
    __syncthreads();                     // B0: A tile ready

    f32x4 acc[4][4];
#pragma unroll
    for (int a = 0; a < 4; ++a)
#pragma unroll
        for (int u = 0; u < 4; ++u) acc[a][u] = (f32x4){0.f, 0.f, 0.f, 0.f};

    // ---- GEMM: A @ W2b (streamed B, barrier-free) ----
#pragma unroll
    for (int ks = 0; ks < 8; ++ks) {
        if (ks < 7) {
#pragma unroll
            for (int u = 0; u < 4; ++u)
                bnxt[u] = *(const bf16x8*)(W2W + (ks + 1) * 2048 + u * 512 + lane * 8);
        }
        bf16x8 afr[4];
#pragma unroll
        for (int a = 0; a < 4; ++a)
            afr[a] = *(const bf16x8*)&h1s[ks * 2048 + (a * 16 + l15) * 32 + xq8];
#pragma unroll
        for (int a = 0; a < 4; ++a)
#pragma unroll
            for (int u = 0; u < 4; ++u)
                acc[a][u] = __builtin_amdgcn_mfma_f32_16x16x32_bf16(afr[a], bcur[u], acc[a][u], 0, 0, 0);
#pragma unroll
        for (int u = 0; u < 4; ++u) bcur[u] = bnxt[u];
    }
    __syncthreads();                     // B1: all GEMM LDS reads done

    // epilogue: ELU + BN stats + write into swizzled layout
#pragma unroll
    for (int u = 0; u < 4; ++u) {
        const int col = wave * 64 + u * 16 + l15;
        const float bv = b2[col];
        const int ks = wave * 2 + (u >> 1);
        const int qw = (u & 1) * 2 + (l15 >> 3);
        const int j  = l15 & 7;
        float s = 0.f, q = 0.f;
#pragma unroll
        for (int a = 0; a < 4; ++a)
#pragma unroll
            for (int r = 0; r < 4; ++r) {
                float v = elu(acc[a][u][r] + bv);
                int rw = a * 16 + quad * 4 + r;
                int qp = qw ^ ((rw >> 1) & 3);
                h1s[ks * 2048 + rw * 32 + qp * 8 + j] = (bf16_t)v;
                s += v; q += v * v;
            }
        s += __shfl_xor(s, 16); s += __shfl_xor(s, 32);
        q += __shfl_xor(q, 16); q += __shfl_xor(q, 32);
        if (quad == 0) { atomicAdd(&sred[col], s); atomicAdd(&sred[256 + col], q); }
    }
    __syncthreads();                     // B2: outputs staged

    // coalesced store from swizzled layout
#pragma unroll
    for (int p = 0; p < 8; ++p) {
        int idx = p * 256 + tid;
        int r = idx >> 5, ch = idx & 31;
        *(uint4*)&out[(size_t)(m0 + r) * H + ch * 8] =
            *(const uint4*)&h1s[(ch >> 2) * 2048 + r * 32 + (((ch & 3) ^ ((r >> 1) & 3)) * 8)];
    }
    atomicAdd(&stats[tid],     sred[tid]);
    atomicAdd(&stats[H + tid], sred[256 + tid]);
}

// ---------------------------------------------------------------------------
// MLP4 fused (R11 winner): streamed fragment-order B + RS-init-acc + async
// swizzled-chunk staging; RS indices block-uniform; 5 barriers.
// ---------------------------------------------------------------------------
__global__ __launch_bounds__(256, 3)
void m4_kernel(const bf16_t* __restrict__ h2, const bf16_t* __restrict__ Wskf,
               const float* __restrict__ RS, const bf16_t* __restrict__ W4f,
               const float* __restrict__ b2, bf16_t* __restrict__ out,
               float* __restrict__ stats)
{
    const int m0 = blockIdx.x * 64;
    const int tid = threadIdx.x, wave = tid >> 6, lane = tid & 63;
    const int l15 = lane & 15, quad = lane >> 4;
    const int row = tid >> 2;
    const int cx8 = (((tid & 3) ^ ((tid >> 3) & 3))) * 8;
    const int xq8 = (quad ^ ((l15 >> 1) & 3)) * 8;

    __shared__ bf16_t h1s[8 * 2048];     // 8 ks-chunks x [64 rows][32 cols], swizzled
    __shared__ float  sred[512];

    sred[tid] = 0.f; sred[256 + tid] = 0.f;

    // block-uniform edge decomposition (SALU): bb, e0, sn0, rr0
    const int bb  = m0 / EB;
    const int e0  = m0 - bb * EB;
    const int sn0 = e0 / (NB - 1);
    const int rr0 = e0 - sn0 * (NB - 1);
    const float* RSb = RS + (size_t)(bb * NB) * 512;

    // async-stage full h2 tile: 8 x global_load_lds per thread (no reg roundtrip)
#pragma unroll
    for (int ks = 0; ks < 8; ++ks)
        load_lds16(h2 + (size_t)(m0 + row) * 256 + ks * 32 + cx8,
                   h1s + ks * 2048 + wave * 512);

    // acc init = S + R, loads issued pre-barrier (latency hides under stage)
    f32x4 acc[4][4];
#pragma unroll
    for (int a = 0; a < 4; ++a)
#pragma unroll
        for (int r = 0; r < 4; ++r) {
            int ro = a * 16 + quad * 4 + r;
            int t  = rr0 + ro;
            int wrap = (t >= NB - 1) ? 1 : 0;
            int sn = sn0 + wrap;
            int rr = t - (wrap ? (NB - 1) : 0);
            int rc = rr + (rr >= sn ? 1 : 0);
            const float* Srow = RSb + (size_t)sn * 512;
            const float* Rrow = RSb + (size_t)rc * 512 + 256;
#pragma unroll
            for (int u = 0; u < 4; ++u) {
                int co = wave * 64 + u * 16 + l15;
                acc[a][u][r] = Srow[co] + Rrow[co];
            }
        }

    // per-wave fragment-order weight bases
    const bf16_t* WskW = Wskf + (size_t)wave * 16384;
    const bf16_t* W4W  = W4f  + (size_t)wave * 16384;

    bf16x8 bcur[4], bnxt[4];
#pragma unroll
    for (int u = 0; u < 4; ++u)
        bcur[u] = *(const bf16x8*)(WskW + u * 512 + lane * 8);
    __syncthreads();                     // B0: stage drained, RS in acc

    // ---- GEMM1: h2_tile @ Wsk (streamed B; acc carries S+R) ----
#pragma unroll
    for (int ks = 0; ks < 8; ++ks) {
        if (ks < 7) {
#pragma unroll
            for (int u = 0; u < 4; ++u)
                bnxt[u] = *(const bf16x8*)(WskW + (ks + 1) * 2048 + u * 512 + lane * 8);
        }
        bf16x8 afr[4];
#pragma unroll
        for (int a = 0; a < 4; ++a)
            afr[a] = *(const bf16x8*)&h1s[ks * 2048 + (a * 16 + l15) * 32 + xq8];
#pragma unroll
        for (int a = 0; a < 4; ++a)
#pragma unroll
            for (int u = 0; u < 4; ++u)
                acc[a][u] = __builtin_amdgcn_mfma_f32_16x16x32_bf16(afr[a], bcur[u], acc[a][u], 0, 0, 0);
#pragma unroll
        for (int u = 0; u < 4; ++u) bcur[u] = bnxt[u];
    }

    // prefetch GEMM2 ks=0 (hides under h3 spill)
#pragma unroll
    for (int u = 0; u < 4; ++u)
        bcur[u] = *(const bf16x8*)(W4W + u * 512 + lane * 8);
    __syncthreads();                     // B1: all GEMM1 LDS reads done

    // h3 = ELU(acc) spilled into the SAME swizzled chunk layout
#pragma unroll
    for (int u = 0; u < 4; ++u) {
        const int ks = wave * 2 + (u >> 1);
        const int qw = (u & 1) * 2 + (l15 >> 3);
        const int j  = l15 & 7;
#pragma unroll
        for (int a = 0; a < 4; ++a)
#pragma unroll
            for (int r = 0; r < 4; ++r) {
                int rw = a * 16 + quad * 4 + r;
                int qp = qw ^ ((rw >> 1) & 3);
                h1s[ks * 2048 + rw * 32 + qp * 8 + j] = (bf16_t)elu(acc[a][u][r]);
            }
    }
    __syncthreads();                     // B2: h3 tile ready

    // ---- GEMM2: h3_tile @ W4b (streamed B) ----
#pragma unroll
    for (int a = 0; a < 4; ++a)
#pragma unroll
        for (int u = 0; u < 4; ++u) acc[a][u] = (f32x4){0.f, 0.f, 0.f, 0.f};
#pragma unroll
    for (int ks = 0; ks < 8; ++ks) {
        if (ks < 7) {
#pragma unroll
            for (int u = 0; u < 4; ++u)
                bnxt[u] = *(const bf16x8*)(W4W + (ks + 1) * 2048 + u * 512 + lane * 8);
        }
        bf16x8 afr[4];
#pragma unroll
        for (int a = 0; a < 4; ++a)
            afr[a] = *(const bf16x8*)&h1s[ks * 2048 + (a * 16 + l15) * 32 + xq8];
#pragma unroll
        for (int a = 0; a < 4; ++a)
#pragma unroll
            for (int u = 0; u < 4; ++u)
                acc[a][u] = __builtin_amdgcn_mfma_f32_16x16x32_bf16(afr[a], bcur[u], acc[a][u], 0, 0, 0);
#pragma unroll
        for (int u = 0; u < 4; ++u) bcur[u] = bnxt[u];
    }
    __syncthreads();                     // B3: all GEMM2 LDS reads done

    // epilogue: ELU + BN stats + write into swizzled layout
#pragma unroll
    for (int u = 0; u < 4; ++u) {
        const int col = wave * 64 + u * 16 + l15;
        const float bv = b2[col];
        const int ks = wave * 2 + (u >> 1);
        const int qw = (u & 1) * 2 + (l15 >> 3);
        const int j  = l15 & 7;
        float s = 0.f, q = 0.f;
#pragma unroll
        for (int a = 0; a < 4; ++a)
#pragma unroll
            for (int r = 0; r < 4; ++r) {
                float v = elu(acc[a][u][r] + bv);
                int rw = a * 16 + quad * 4 + r;
                int qp = qw ^ ((rw >> 1) & 3);
                h1s[ks * 2048 + rw * 32 + qp * 8 + j] = (bf16_t)v;
                s += v; q += v * v;
            }
        s += __shfl_xor(s, 16); s += __shfl_xor(s, 32);
        q += __shfl_xor(q, 16); q += __shfl_xor(q, 32);
        if (quad == 0) { atomicAdd(&sred[col], s); atomicAdd(&sred[256 + col], q); }
    }
    __syncthreads();                     // B4: outputs staged

    // coalesced store from swizzled layout
#pragma unroll
    for (int p = 0; p < 8; ++p) {
        int idx = p * 256 + tid;
        int r = idx >> 5, ch = idx & 31;
        *(uint4*)&out[(size_t)(m0 + r) * H + ch * 8] =
            *(const uint4*)&h1s[(ch >> 2) * 2048 + r * 32 + (((ch & 3) ^ ((r >> 1) & 3)) * 8)];
    }
    atomicAdd(&stats[tid],     sred[tid]);
    atomicAdd(&stats[H + tid], sred[256 + tid]);
}

// ---------------------------------------------------------------------------
// prep: all static weight prep in ONE kernel (block-index dispatch).
// ALL six 256x256 weights (w1a,w1b,w2b,w3a,w3b,w4b) now emit FRAGMENT ORDER:
// dst = wave*16384 + ks*2048 + u*512 + lane*8 + j, with
// n = wave*64+u*16+l15, k = ks*32+quad*8+j, lane = quad*16+l15.
// ---------------------------------------------------------------------------
__global__ void prep(const float* __restrict__ w1a, bf16_t* __restrict__ wt1a,
                     const float* __restrict__ w1b, bf16_t* __restrict__ wt1b,
                     const float* __restrict__ w2b, bf16_t* __restrict__ wt2b,
                     const float* __restrict__ w3a, bf16_t* __restrict__ wt3a,
                     const float* __restrict__ w3b, bf16_t* __restrict__ wt3b,
                     const float* __restrict__ w4b, bf16_t* __restrict__ wt4b,
                     const float* __restrict__ w2a, bf16_t* __restrict__ wtpq,
                     const float* __restrict__ w4a, bf16_t* __restrict__ wtrs,
                     const float* __restrict__ b2a, float* __restrict__ biasPQ,
                     float* __restrict__ stats)
{
    int blk = blockIdx.x, tid = threadIdx.x;
    if (blk < 1536) {
        int grp = blk >> 8, lb = blk & 255;
        int idx = lb * 256 + tid;
        int k = idx >> 8, n = idx & 255;
        const float* w; bf16_t* wt;
        switch (grp) {
            case 0: w = w1a; wt = wt1a; break;
            case 1: w = w1b; wt = wt1b; break;
            case 2: w = w2b; wt = wt2b; break;
            case 3: w = w3a; wt = wt3a; break;
            case 4: w = w3b; wt = wt3b; break;
            default: w = w4b; wt = wt4b; break;
        }
        int wv = n >> 6, u = (n >> 4) & 3, l15 = n & 15;
        int ks = k >> 5, qd = (k >> 3) & 3, j = k & 7;
        wt[wv * 16384 + ks * 2048 + u * 512 + (qd * 16 + l15) * 8 + j] = (bf16_t)w[idx];
    } else if (blk < 2560) {
        int lb = blk - 1536;
        const float* w = (lb < 512) ? w2a : w4a;
        bf16_t* wt = (lb < 512) ? wtpq : wtrs;
        int c = lb & 511, k = tid;
        float v = (c < 256) ? w[k * 256 + c] : w[(256 + k) * 256 + (c - 256)];
        wt[c * 256 + k] = (bf16_t)v;
    } else if (blk == 2560) {
        biasPQ[tid] = b2a[tid];
        biasPQ[256 + tid] = 0.f;
    } else {
        for (int j = 0; j < 8; ++j) stats[j * 256 + tid] = 0.f;
    }
}

// prep2: blocks 0-255 build wsk in FRAGMENT ORDER (n=blk, k=tid); block 256
// builds bias_rs. sc2 computed in-kernel from raw stats2.
__global__ void prep2(const float* __restrict__ w4a, const float* __restrict__ stats2,
                      const float* __restrict__ g2, const float* __restrict__ be2,
                      const float* __restrict__ b4a, bf16_t* __restrict__ wt,
                      float* __restrict__ bias)
{
    __shared__ float sh2s[256];
    int blk = blockIdx.x, tid = threadIdx.x;
    float mean = stats2[tid] / (float)M_EDGE;
    float var  = stats2[256 + tid] / (float)M_EDGE - mean * mean;
    float scl  = g2[tid] * rsqrtf(var + BN_EPS);
    if (blk < 256) {
        int n = blk, k = tid;
        int wv = n >> 6, u = (n >> 4) & 3, l15 = n & 15;
        int ks = k >> 5, qd = (k >> 3) & 3, j = k & 7;
        wt[wv * 16384 + ks * 2048 + u * 512 + (qd * 16 + l15) * 8 + j] =
            (bf16_t)(w4a[(512 + tid) * 256 + blk] * scl);
    } else {
        sh2s[tid] = be2[tid] - mean * scl;
        __syncthreads();
        float acc = 0.f;
        for (int k = 0; k < 256; ++k)
            acc += sh2s[k] * w4a[(512 + k) * 256 + tid];
        bias[tid] = b4a[tid] + acc;
        bias[256 + tid] = 0.f;
    }
}

// edge2node w/ inline BN2 finalize
__global__ void edge2node(const bf16_t* __restrict__ x2, const float* __restrict__ stats2,
                          const float* __restrict__ g2, const float* __restrict__ be2,
                          bf16_t* __restrict__ inc)
{
    int bn = blockIdx.x, bb = bn >> 6, n = bn & 63;
    int g = threadIdx.x >> 5, t = threadIdx.x & 31;
    __shared__ float part[8][256];
    __shared__ float ss[512];
    {
        int c = threadIdx.x;
        float mean = stats2[c] / (float)M_EDGE;
        float var  = stats2[256 + c] / (float)M_EDGE - mean * mean;
        float scl  = g2[c] * rsqrtf(var + BN_EPS);
        ss[c]       = scl;
        ss[256 + c] = be2[c] - mean * scl;
    }
    const bf16_t* base = x2 + (size_t)bb * EB * H;
    float a[8] = {0.f,0.f,0.f,0.f,0.f,0.f,0.f,0.f};
    for (int i = g; i < NB; i += 8) {
        if (i == n) continue;
        int e = i * (NB - 1) + n - (n > i ? 1 : 0);
        bf16x8 v = *(const bf16x8*)&base[(size_t)e * H + t * 8];
#pragma unroll
        for (int j = 0; j < 8; ++j) a[j] += (float)v[j];
    }
#pragma unroll
    for (int j = 0; j < 8; ++j) part[g][t * 8 + j] = a[j];
    __syncthreads();
    int c = threadIdx.x;
    float s = 0.f;
#pragma unroll
    for (int g2i = 0; g2i < 8; ++g2i) s += part[g2i][c];
    inc[(size_t)bn * H + c] = (bf16_t)(s * (1.f / 64.f) * ss[c] + ss[256 + c] * (63.f / 64.f));
}

// fc w/ inline BN4 finalize
__global__ void fc_kernel(const bf16_t* __restrict__ x4, const float* __restrict__ stats4,
                          const float* __restrict__ g4, const float* __restrict__ be4,
                          const float* __restrict__ fcw, const float* __restrict__ fcb,
                          float* __restrict__ out)
{
    __shared__ float ss[512];
    {
        int c = threadIdx.x;
        float mean = stats4[c] / (float)M_EDGE;
        float var  = stats4[256 + c] / (float)M_EDGE - mean * mean;
        float scl  = g4[c] * rsqrtf(var + BN_EPS);
        ss[c]       = scl;
        ss[256 + c] = be4[c] - mean * scl;
    }
    __syncthreads();
    int row  = blockIdx.x * 8 + (threadIdx.x >> 5);
    int t    = threadIdx.x & 31;
    bf16x8 v8 = *(const bf16x8*)(x4 + (size_t)row * H + t * 8);
    float s0 = 0.f, s1 = 0.f;
#pragma unroll
    for (int j = 0; j < 8; ++j) {
        int c = t * 8 + j;
        float v = (float)v8[j] * ss[c] + ss[256 + c];
        s0 += v * fcw[c * 2];
        s1 += v * fcw[c * 2 + 1];
    }
#pragma unroll
    for (int off = 16; off; off >>= 1) {
        s0 += __shfl_down(s0, off, 32);
        s1 += __shfl_down(s1, off, 32);
    }
    if (t == 0) {
        out[(size_t)row * 2]     = s0 + fcb[0];
        out[(size_t)row * 2 + 1] = s1 + fcb[1];
    }
}

// ---------------------------------------------------------------------------
extern "C" void kernel_launch(void* const* d_in, const int* in_sizes, int n_in,
                              void* d_out, int out_size, void* d_ws, size_t ws_size,
                              hipStream_t stream)
{
    (void)in_sizes; (void)n_in; (void)out_size; (void)ws_size;
    const float* inp = (const float*)d_in[0];
    const float* w1a = (const float*)d_in[3];  const float* b1a = (const float*)d_in[4];
    const float* w1b = (const float*)d_in[5];  const float* b1b = (const float*)d_in[6];
    const float* g1  = (const float*)d_in[7];  const float* be1 = (const float*)d_in[8];
    const float* w2a = (const float*)d_in[9];  const float* b2a = (const float*)d_in[10];
    const float* w2b = (const float*)d_in[11]; const float* b2b = (const float*)d_in[12];
    const float* g2  = (const float*)d_in[13]; const float* be2 = (const float*)d_in[14];
    const float* w3a = (const float*)d_in[15]; const float* b3a = (const float*)d_in[16];
    const float* w3b = (const float*)d_in[17]; const float* b3b = (const float*)d_in[18];
    const float* g3  = (const float*)d_in[19]; const float* be3 = (const float*)d_in[20];
    const float* w4a = (const float*)d_in[21]; const float* b4a = (const float*)d_in[22];
    const float* w4b = (const float*)d_in[23]; const float* b4b = (const float*)d_in[24];
    const float* g4  = (const float*)d_in[25]; const float* be4 = (const float*)d_in[26];
    const float* fcw = (const float*)d_in[27]; const float* fcb = (const float*)d_in[28];

    char* p = (char*)d_ws;
    auto alloc = [&](size_t nbytes) { char* r = p; p += (nbytes + 255) & ~(size_t)255; return r; };

    bf16_t* wt1a = (bf16_t*)alloc(256 * 256 * 2);
    bf16_t* wt1b = (bf16_t*)alloc(256 * 256 * 2);
    bf16_t* wt2b = (bf16_t*)alloc(256 * 256 * 2);
    bf16_t* wt3a = (bf16_t*)alloc(256 * 256 * 2);
    bf16_t* wt3b = (bf16_t*)alloc(256 * 256 * 2);
    bf16_t* wt4b = (bf16_t*)alloc(256 * 256 * 2);
    bf16_t* wtpq = (bf16_t*)alloc(512 * 256 * 2);
    bf16_t* wtrs = (bf16_t*)alloc(512 * 256 * 2);
    bf16_t* wtsk = (bf16_t*)alloc(256 * 256 * 2);
    float*  biasPQ = (float*)alloc(512 * sizeof(float));
    float*  biasRS = (float*)alloc(512 * sizeof(float));
    float*  stats  = (float*)alloc(4 * 512 * sizeof(float));
    bf16_t* x1   = (bf16_t*)alloc((size_t)M_NODE * H * 2);
    bf16_t* incb = (bf16_t*)alloc((size_t)M_NODE * H * 2);
    bf16_t* x3   = (bf16_t*)alloc((size_t)M_NODE * H * 2);
    float*  PQ   = (float*)alloc((size_t)M_NODE * 512 * sizeof(float));
    float*  RS   = (float*)alloc((size_t)M_NODE * 512 * sizeof(float));
    bf16_t* h2   = (bf16_t*)alloc((size_t)M_EDGE * H * 2);
    bf16_t* h4   = (bf16_t*)alloc((size_t)M_EDGE * H * 2);

    // all static prep in one launch
    prep<<<2562, 256, 0, stream>>>(w1a, wt1a, w1b, wt1b, w2b, wt2b, w3a, wt3a,
                                   w3b, wt3b, w4b, wt4b, w2a, wtpq, w4a, wtrs,
                                   b2a, biasPQ, stats);

    // MLP1 (nodes, streamed fragment-order B) -> x1, stats1
    fused_mlp<true ><<<M_NODE / 64, 256, 0, stream>>>(inp, wt1a, b1a, wt1b, b1b, x1, stats + 0);

    // PQ = BN1(x1) @ [W2a_s | W2a_r] + [b2a|0]  (BN1 finalize+fold inline)
    { dim3 g(M_NODE / 64, 2);
      node_gemm<<<g, 256, 0, stream>>>(x1, stats + 0, g1, be1, (float)M_NODE, wtpq, biasPQ, PQ); }

    // MLP2 (edges, streamed fragment-order B + swizzled LDS, T=1) -> h2, stats2
    m2_kernel<<<M_EDGE / 64, 256, 0, stream>>>(PQ, wt2b, b2b, h2, stats + 512);

    // edge2node (BN2 finalize+fold inline) + MLP3 (nodes, streamed B)
    edge2node<<<M_NODE, 256, 0, stream>>>(h2, stats + 512, g2, be2, incb);
    fused_mlp<false><<<M_NODE / 64, 256, 0, stream>>>(incb, wt3a, b3a, wt3b, b3b, x3, stats + 1024);

    // BN2-folded skip weight (fragment order) + RS bias
    prep2<<<257, 256, 0, stream>>>(w4a, stats + 512, g2, be2, b4a, wtsk, biasRS);
    // RS = BN3(x3) @ [W4a_s | W4a_r] + biasRS  (BN3 finalize+fold inline)
    { dim3 g(M_NODE / 64, 2);
      node_gemm<<<g, 256, 0, stream>>>(x3, stats + 1024, g3, be3, (float)M_NODE, wtrs, biasRS, RS); }

    // MLP4 (edges, streamed B + RS-init-acc + async swizzled stage) -> h4, stats4
    m4_kernel<<<M_EDGE / 64, 256, 0, stream>>>(h2, wtsk, RS, wt4b, b4b, h4, stats + 1536);

    // final fc with BN4 finalize+fold inline, fp32 output
    fc_kernel<<<M_EDGE / 8, 256, 0, stream>>>(h4, stats + 1536, g4, be4, fcw, fcb, (float*)d_out);
}

// Round 13
// 340.025 us; speedup vs baseline: 1.0375x; 1.0375x over previous
//
#include <hip/hip_runtime.h>

typedef __bf16 bf16_t;
typedef __bf16 bf16x8 __attribute__((ext_vector_type(8)));
typedef float  f32x4  __attribute__((ext_vector_type(4)));

#define NB    64
#define EB    4032            // NB*(NB-1)
#define BATCH 32
#define H     256
#define M_EDGE (BATCH*EB)     // 129024
#define M_NODE (BATCH*NB)     // 2048
#define BN_EPS 1e-5f

__device__ __forceinline__ void load_lds16(const void* g, void* l) {
    __builtin_amdgcn_global_load_lds(
        (const __attribute__((address_space(1))) unsigned int*)g,
        (__attribute__((address_space(3))) unsigned int*)l, 16, 0, 0);
}
// fast ELU: v_exp_f32 (+mul) instead of ~35-inst expm1f; bf16-rounding dwarfs the error
__device__ __forceinline__ float elu(float v) { return v > 0.f ? v : __expf(v) - 1.f; }

// ---------------------------------------------------------------------------
// Fused 2-layer node MLP, STREAMED-B, M-TILE 32 (R13): grid 64 blocks (one
// residency round -> wall = per-block latency; halving the tile halves the
// serial chain). Structure identical to R9 winner otherwise; acc[2][4].
// ---------------------------------------------------------------------------
template<bool AF32>
__global__ __launch_bounds__(256, 3)
void fused_mlp(const void* __restrict__ A0v,
               const bf16_t* __restrict__ W1f, const float* __restrict__ b1,
               const bf16_t* __restrict__ W2f, const float* __restrict__ b2,
               bf16_t* __restrict__ out, float* __restrict__ stats)
{
    const int m0 = blockIdx.x * 32;
    const int tid = threadIdx.x, wave = tid >> 6, lane = tid & 63;
    const int l15 = lane & 15, quad = lane >> 4;
    const int row = tid >> 3;            // 0..31
    const int c0 = (tid & 7) * 32;       // 8 threads/row x 32 cols

    __shared__ bf16_t h1s[32 * 264];
    __shared__ float  sred[512];

    sred[tid] = 0.f; sred[256 + tid] = 0.f;

    // stage A tile (32x256) into padded LDS
    if (AF32) {
        const float* af = (const float*)A0v + (size_t)(m0 + row) * 256 + c0;
#pragma unroll
        for (int j = 0; j < 4; ++j) {
            float4 lo = *(const float4*)(af + j * 8);
            float4 hi = *(const float4*)(af + j * 8 + 4);
            bf16x8 v;
            v[0]=(bf16_t)lo.x; v[1]=(bf16_t)lo.y; v[2]=(bf16_t)lo.z; v[3]=(bf16_t)lo.w;
            v[4]=(bf16_t)hi.x; v[5]=(bf16_t)hi.y; v[6]=(bf16_t)hi.z; v[7]=(bf16_t)hi.w;
            *(bf16x8*)&h1s[row * 264 + c0 + j * 8] = v;
        }
    } else {
        const bf16_t* src = (const bf16_t*)A0v + (size_t)(m0 + row) * 256 + c0;
#pragma unroll
        for (int j = 0; j < 4; ++j)
            *(bf16x8*)&h1s[row * 264 + c0 + j * 8] = *(const bf16x8*)(src + j * 8);
    }

    // per-wave fragment-order bases
    const bf16_t* W1W = W1f + (size_t)wave * 16384;
    const bf16_t* W2W = W2f + (size_t)wave * 16384;

    bf16x8 bcur[4], bnxt[4];
#pragma unroll
    for (int u = 0; u < 4; ++u)
        bcur[u] = *(const bf16x8*)(W1W + u * 512 + lane * 8);
    __syncthreads();                     // A tile ready (B ks=0 in flight)

    f32x4 acc[2][4];
#pragma unroll
    for (int a = 0; a < 2; ++a)
#pragma unroll
        for (int u = 0; u < 4; ++u) acc[a][u] = (f32x4){0.f, 0.f, 0.f, 0.f};

    // ---- layer 1: A @ W1 (streamed B, barrier-free) ----
#pragma unroll
    for (int ks = 0; ks < 8; ++ks) {
        if (ks < 7) {
#pragma unroll
            for (int u = 0; u < 4; ++u)
                bnxt[u] = *(const bf16x8*)(W1W + (ks + 1) * 2048 + u * 512 + lane * 8);
        }
        bf16x8 afr[2];
#pragma unroll
        for (int a = 0; a < 2; ++a)
            afr[a] = *(const bf16x8*)&h1s[(a * 16 + l15) * 264 + ks * 32 + quad * 8];
#pragma unroll
        for (int a = 0; a < 2; ++a)
#pragma unroll
            for (int u = 0; u < 4; ++u)
                acc[a][u] = __builtin_amdgcn_mfma_f32_16x16x32_bf16(afr[a], bcur[u], acc[a][u], 0, 0, 0);
#pragma unroll
        for (int u = 0; u < 4; ++u) bcur[u] = bnxt[u];
    }

    // prefetch layer-2 ks=0 (hides under h1 spill)
#pragma unroll
    for (int u = 0; u < 4; ++u)
        bcur[u] = *(const bf16x8*)(W2W + u * 512 + lane * 8);
    __syncthreads();                     // B1: all layer-1 LDS reads done

    // h1 = ELU(acc + b1), spilled to LDS row-major
#pragma unroll
    for (int u = 0; u < 4; ++u) {
        int   col = wave * 64 + u * 16 + l15;
        float bv  = b1[col];
#pragma unroll
        for (int a = 0; a < 2; ++a)
#pragma unroll
            for (int r = 0; r < 4; ++r)
                h1s[(a * 16 + quad * 4 + r) * 264 + col] = (bf16_t)elu(acc[a][u][r] + bv);
    }
    __syncthreads();                     // B2: h1 visible

    // ---- layer 2: h1 @ W2 (streamed B, barrier-free) ----
#pragma unroll
    for (int a = 0; a < 2; ++a)
#pragma unroll
        for (int u = 0; u < 4; ++u) acc[a][u] = (f32x4){0.f, 0.f, 0.f, 0.f};
#pragma unroll
    for (int ks = 0; ks < 8; ++ks) {
        if (ks < 7) {
#pragma unroll
            for (int u = 0; u < 4; ++u)
                bnxt[u] = *(const bf16x8*)(W2W + (ks + 1) * 2048 + u * 512 + lane * 8);
        }
        bf16x8 afr[2];
#pragma unroll
        for (int a = 0; a < 2; ++a)
            afr[a] = *(const bf16x8*)&h1s[(a * 16 + l15) * 264 + ks * 32 + quad * 8];
#pragma unroll
        for (int a = 0; a < 2; ++a)
#pragma unroll
            for (int u = 0; u < 4; ++u)
                acc[a][u] = __builtin_amdgcn_mfma_f32_16x16x32_bf16(afr[a], bcur[u], acc[a][u], 0, 0, 0);
#pragma unroll
        for (int u = 0; u < 4; ++u) bcur[u] = bnxt[u];
    }
    __syncthreads();                     // B3: all layer-2 LDS reads done

    // epilogue: ELU + BN stats + bf16 write-back
#pragma unroll
    for (int u = 0; u < 4; ++u) {
        int   col = wave * 64 + u * 16 + l15;
        float bv  = b2[col];
        float s = 0.f, q = 0.f;
#pragma unroll
        for (int a = 0; a < 2; ++a)
#pragma unroll
            for (int r = 0; r < 4; ++r) {
                float v = elu(acc[a][u][r] + bv);
                h1s[(a * 16 + quad * 4 + r) * 264 + col] = (bf16_t)v;
                s += v; q += v * v;
            }
        s += __shfl_xor(s, 16); s += __shfl_xor(s, 32);
        q += __shfl_xor(q, 16); q += __shfl_xor(q, 32);
        if (quad == 0) { atomicAdd(&sred[col], s); atomicAdd(&sred[256 + col], q); }
    }
    __syncthreads();                     // B4: outputs staged

#pragma unroll
    for (int p = 0; p < 4; ++p) {
        int idx = p * 256 + tid;
        int r = idx >> 5, ch = idx & 31;
        *(uint4*)&out[(size_t)(m0 + r) * H + ch * 8] = *(const uint4*)&h1s[r * 264 + ch * 8];
    }
    atomicAdd(&stats[tid],     sred[tid]);
    atomicAdd(&stats[H + tid], sred[256 + tid]);
}

// ---------------------------------------------------------------------------
// Node GEMM (R13): STREAMED fragment-order B + one-shot BN-folded A staging
// into swizzled chunks (8x[32][32]); M-tile 32, grid (64,2); 2 barriers
// (was 16). out[M,512] = (A*scale+shift)[M,256] @ W^T + bias, fp32 out.
// Numerics identical (same bf16 fold, same ks order).
// ---------------------------------------------------------------------------
__global__ __launch_bounds__(256, 3)
void node_gemm(const bf16_t* __restrict__ A, const float* __restrict__ statsIn,
               const float* __restrict__ g, const float* __restrict__ beta, float Mcnt,
               const bf16_t* __restrict__ Wf, const float* __restrict__ bias,
               float* __restrict__ out)
{
    const int m0 = blockIdx.x * 32;
    const int nb = blockIdx.y * 256;
    const int tid = threadIdx.x, wave = tid >> 6, lane = tid & 63;
    const int l15 = lane & 15, quad = lane >> 4;
    const int row = tid >> 3;            // 0..31
    const int c0 = (tid & 7) * 32;
    const int xq8 = (quad ^ ((l15 >> 1) & 3)) * 8;

    __shared__ bf16_t As[8 * 1024];      // 8 ks-chunks x [32][32], swizzled
    __shared__ float  ss[512];           // scale | shift

    {   // BN finalize inline
        float mean = statsIn[tid] / Mcnt;
        float var  = statsIn[256 + tid] / Mcnt - mean * mean;
        float scl  = g[tid] * rsqrtf(var + BN_EPS);
        ss[tid]       = scl;
        ss[256 + tid] = beta[tid] - mean * scl;
    }
    __syncthreads();                     // B0: ss ready

    // BN-folded A staging into swizzled chunks (VGPR path)
    {
        const bf16_t* Ar = A + (size_t)(m0 + row) * 256 + c0;
        const int rs = (row >> 1) & 3;
#pragma unroll
        for (int j = 0; j < 4; ++j) {
            int c = c0 + j * 8;
            bf16x8 v = *(const bf16x8*)(Ar + j * 8);
            bf16x8 w;
#pragma unroll
            for (int e = 0; e < 8; ++e)
                w[e] = (bf16_t)((float)v[e] * ss[c + e] + ss[256 + c + e]);
            *(bf16x8*)&As[(c >> 5) * 1024 + row * 32 + ((((c >> 3) & 3) ^ rs) * 8)] = w;
        }
    }

    // per-half, per-wave fragment-order weight base
    const bf16_t* WW = Wf + (size_t)blockIdx.y * 65536 + (size_t)wave * 16384;
    bf16x8 bcur[4], bnxt[4];
#pragma unroll
    for (int u = 0; u < 4; ++u)
        bcur[u] = *(const bf16x8*)(WW + u * 512 + lane * 8);
    __syncthreads();                     // B1: A staged

    f32x4 acc[2][4];
#pragma unroll
    for (int a = 0; a < 2; ++a)
#pragma unroll
        for (int u = 0; u < 4; ++u) acc[a][u] = (f32x4){0.f, 0.f, 0.f, 0.f};

    // ---- GEMM (streamed B, barrier-free) ----
#pragma unroll
    for (int ks = 0; ks < 8; ++ks) {
        if (ks < 7) {
#pragma unroll
            for (int u = 0; u < 4; ++u)
                bnxt[u] = *(const bf16x8*)(WW + (ks + 1) * 2048 + u * 512 + lane * 8);
        }
        bf16x8 afr[2];
#pragma unroll
        for (int a = 0; a < 2; ++a)
            afr[a] = *(const bf16x8*)&As[ks * 1024 + (a * 16 + l15) * 32 + xq8];
#pragma unroll
        for (int a = 0; a < 2; ++a)
#pragma unroll
            for (int u = 0; u < 4; ++u)
                acc[a][u] = __builtin_amdgcn_mfma_f32_16x16x32_bf16(afr[a], bcur[u], acc[a][u], 0, 0, 0);
#pragma unroll
        for (int u = 0; u < 4; ++u) bcur[u] = bnxt[u];
    }

    // epilogue: + bias, fp32 direct global write (no barrier needed)
#pragma unroll
    for (int u = 0; u < 4; ++u) {
        int col = nb + wave * 64 + u * 16 + l15;
        float bv = bias[col];
#pragma unroll
        for (int a = 0; a < 2; ++a)
#pragma unroll
            for (int r = 0; r < 4; ++r)
                out[(size_t)(m0 + a * 16 + quad * 4 + r) * 512 + col] = acc[a][u][r] + bv;
    }
}

// ---------------------------------------------------------------------------
// MLP2 (R12): streamed fragment-order W2b; computeA writes ELU(P+Q) straight
// into the XOR-swizzled chunk layout (8x[64][32]); block-uniform edge
// decomposition; T=1, grid 2016, 3 barriers/block.
// ---------------------------------------------------------------------------
__global__ __launch_bounds__(256, 3)
void m2_kernel(const float* __restrict__ PQ, const bf16_t* __restrict__ W2f,
               const float* __restrict__ b2, bf16_t* __restrict__ out,
               float* __restrict__ stats)
{
    const int m0 = blockIdx.x * 64;
    const int tid = threadIdx.x, wave = tid >> 6, lane = tid & 63;
    const int l15 = lane & 15, quad = lane >> 4;
    const int row = tid >> 2;
    const int c0 = (tid & 3) * 64;
    const int xq8 = (quad ^ ((l15 >> 1) & 3)) * 8;

    __shared__ bf16_t h1s[8 * 2048];     // 8 ks-chunks x [64 rows][32 cols], swizzled
    __shared__ float  sred[512];

    sred[tid] = 0.f; sred[256 + tid] = 0.f;

    // block-uniform edge decomposition (SALU)
    const int bb  = m0 / EB;
    const int e0  = m0 - bb * EB;
    const int sn0 = e0 / (NB - 1);
    const int rr0 = e0 - sn0 * (NB - 1);

    // computeA: ELU(P+Q) written directly into the swizzled chunk layout
    {
        int t  = rr0 + row;
        int wrap = (t >= NB - 1) ? 1 : 0;
        int sn = sn0 + wrap;
        int rr = t - (wrap ? (NB - 1) : 0);
        int rc = rr + (rr >= sn ? 1 : 0);
        const float* Prow = PQ + (size_t)(bb * NB + sn) * 512;
        const float* Qrow = PQ + (size_t)(bb * NB + rc) * 512 + 256;
        const int rs = ((row >> 1) & 3);
#pragma unroll
        for (int j = 0; j < 8; ++j) {
            int c = c0 + j * 8;
            float4 p0 = *(const float4*)(Prow + c);
            float4 p1 = *(const float4*)(Prow + c + 4);
            float4 q0 = *(const float4*)(Qrow + c);
            float4 q1 = *(const float4*)(Qrow + c + 4);
            bf16x8 v;
            v[0]=(bf16_t)elu(p0.x+q0.x); v[1]=(bf16_t)elu(p0.y+q0.y);
            v[2]=(bf16_t)elu(p0.z+q0.z); v[3]=(bf16_t)elu(p0.w+q0.w);
            v[4]=(bf16_t)elu(p1.x+q1.x); v[5]=(bf16_t)elu(p1.y+q1.y);
            v[6]=(bf16_t)elu(p1.z+q1.z); v[7]=(bf16_t)elu(p1.w+q1.w);
            *(bf16x8*)&h1s[(c >> 5) * 2048 + row * 32 + ((((c >> 3) & 3) ^ rs) * 8)] = v;
        }
    }

    // stream B ks=0 (in flight across the barrier)
    const bf16_t* W2W = W2f + (size_t)wave * 16384;
    bf16x8 bcur[4], bnxt[4];
#pragma unroll
    for (int u = 0; u < 4; ++u)
        bcur[u] = *(const bf16x8*)(W2W + u * 512 + lane * 8);
    __syncthreads();                     // B0: A tile ready

    f32x4 acc[4][4];
#pragma unroll
    for (int a = 0; a < 4; ++a)
#pragma unroll
        for (int u = 0; u < 4; ++u) acc[a][u] = (f32x4){0.f, 0.f, 0.f, 0.f};

    // ---- GEMM: A @ W2b (streamed B, barrier-free) ----
#pragma unroll
    for (int ks = 0; ks < 8; ++ks) {
        if (ks < 7) {
#pragma unroll
            for (int u = 0; u < 4; ++u)
                bnxt[u] = *(const bf16x8*)(W2W + (ks + 1) * 2048 + u * 512 + lane * 8);
        }
        bf16x8 afr[4];
#pragma unroll
        for (int a = 0; a < 4; ++a)
            afr[a] = *(const bf16x8*)&h1s[ks * 2048 + (a * 16 + l15) * 32 + xq8];
#pragma unroll
        for (int a = 0; a < 4; ++a)
#pragma unroll
            for (int u = 0; u < 4; ++u)
                acc[a][u] = __builtin_amdgcn_mfma_f32_16x16x32_bf16(afr[a], bcur[u], acc[a][u], 0, 0, 0);
#pragma unroll
        for (int u = 0; u < 4; ++u) bcur[u] = bnxt[u];
    }
    __syncthreads();                     // B1: all GEMM LDS reads done

    // epilogue: ELU + BN stats + write into swizzled layout
#pragma unroll
    for (int u = 0; u < 4; ++u) {
        const int col = wave * 64 + u * 16 + l15;
        const float bv = b2[col];
        const int ks = wave * 2 + (u >> 1);
        const int qw = (u & 1) * 2 + (l15 >> 3);
        const int j  = l15 & 7;
        float s = 0.f, q = 0.f;
#pragma unroll
        for (int a = 0; a < 4; ++a)
#pragma unroll
            for (int r = 0; r < 4; ++r) {
                float v = elu(acc[a][u][r] + bv);
                int rw = a * 16 + quad * 4 + r;
                int qp = qw ^ ((rw >> 1) & 3);
                h1s[ks * 2048 + rw * 32 + qp * 8 + j] = (bf16_t)v;
                s += v; q += v * v;
            }
        s += __shfl_xor(s, 16); s += __shfl_xor(s, 32);
        q += __shfl_xor(q, 16); q += __shfl_xor(q, 32);
        if (quad == 0) { atomicAdd(&sred[col], s); atomicAdd(&sred[256 + col], q); }
    }
    __syncthreads();                     // B2: outputs staged

    // coalesced store from swizzled layout
#pragma unroll
    for (int p = 0; p < 8; ++p) {
        int idx = p * 256 + tid;
        int r = idx >> 5, ch = idx & 31;
        *(uint4*)&out[(size_t)(m0 + r) * H + ch * 8] =
            *(const uint4*)&h1s[(ch >> 2) * 2048 + r * 32 + (((ch & 3) ^ ((r >> 1) & 3)) * 8)];
    }
    atomicAdd(&stats[tid],     sred[tid]);
    atomicAdd(&stats[H + tid], sred[256 + tid]);
}

// ---------------------------------------------------------------------------
// MLP4 fused (R11 winner): streamed fragment-order B + RS-init-acc + async
// swizzled-chunk staging; RS indices block-uniform; 5 barriers.
// ---------------------------------------------------------------------------
__global__ __launch_bounds__(256, 3)
void m4_kernel(const bf16_t* __restrict__ h2, const bf16_t* __restrict__ Wskf,
               const float* __restrict__ RS, const bf16_t* __restrict__ W4f,
               const float* __restrict__ b2, bf16_t* __restrict__ out,
               float* __restrict__ stats)
{
    const int m0 = blockIdx.x * 64;
    const int tid = threadIdx.x, wave = tid >> 6, lane = tid & 63;
    const int l15 = lane & 15, quad = lane >> 4;
    const int row = tid >> 2;
    const int cx8 = (((tid & 3) ^ ((tid >> 3) & 3))) * 8;
    const int xq8 = (quad ^ ((l15 >> 1) & 3)) * 8;

    __shared__ bf16_t h1s[8 * 2048];     // 8 ks-chunks x [64 rows][32 cols], swizzled
    __shared__ float  sred[512];

    sred[tid] = 0.f; sred[256 + tid] = 0.f;

    // block-uniform edge decomposition (SALU): bb, e0, sn0, rr0
    const int bb  = m0 / EB;
    const int e0  = m0 - bb * EB;
    const int sn0 = e0 / (NB - 1);
    const int rr0 = e0 - sn0 * (NB - 1);
    const float* RSb = RS + (size_t)(bb * NB) * 512;

    // async-stage full h2 tile: 8 x global_load_lds per thread (no reg roundtrip)
#pragma unroll
    for (int ks = 0; ks < 8; ++ks)
        load_lds16(h2 + (size_t)(m0 + row) * 256 + ks * 32 + cx8,
                   h1s + ks * 2048 + wave * 512);

    // acc init = S + R, loads issued pre-barrier (latency hides under stage)
    f32x4 acc[4][4];
#pragma unroll
    for (int a = 0; a < 4; ++a)
#pragma unroll
        for (int r = 0; r < 4; ++r) {
            int ro = a * 16 + quad * 4 + r;
            int t  = rr0 + ro;
            int wrap = (t >= NB - 1) ? 1 : 0;
            int sn = sn0 + wrap;
            int rr = t - (wrap ? (NB - 1) : 0);
            int rc = rr + (rr >= sn ? 1 : 0);
            const float* Srow = RSb + (size_t)sn * 512;
            const float* Rrow = RSb + (size_t)rc * 512 + 256;
#pragma unroll
            for (int u = 0; u < 4; ++u) {
                int co = wave * 64 + u * 16 + l15;
                acc[a][u][r] = Srow[co] + Rrow[co];
            }
        }

    // per-wave fragment-order weight bases
    const bf16_t* WskW = Wskf + (size_t)wave * 16384;
    const bf16_t* W4W  = W4f  + (size_t)wave * 16384;

    bf16x8 bcur[4], bnxt[4];
#pragma unroll
    for (int u = 0; u < 4; ++u)
        bcur[u] = *(const bf16x8*)(WskW + u * 512 + lane * 8);
    __syncthreads();                     // B0: stage drained, RS in acc

    // ---- GEMM1: h2_tile @ Wsk (streamed B; acc carries S+R) ----
#pragma unroll
    for (int ks = 0; ks < 8; ++ks) {
        if (ks < 7) {
#pragma unroll
            for (int u = 0; u < 4; ++u)
                bnxt[u] = *(const bf16x8*)(WskW + (ks + 1) * 2048 + u * 512 + lane * 8);
        }
        bf16x8 afr[4];
#pragma unroll
        for (int a = 0; a < 4; ++a)
            afr[a] = *(const bf16x8*)&h1s[ks * 2048 + (a * 16 + l15) * 32 + xq8];
#pragma unroll
        for (int a = 0; a < 4; ++a)
#pragma unroll
            for (int u = 0; u < 4; ++u)
                acc[a][u] = __builtin_amdgcn_mfma_f32_16x16x32_bf16(afr[a], bcur[u], acc[a][u], 0, 0, 0);
#pragma unroll
        for (int u = 0; u < 4; ++u) bcur[u] = bnxt[u];
    }

    // prefetch GEMM2 ks=0 (hides under h3 spill)
#pragma unroll
    for (int u = 0; u < 4; ++u)
        bcur[u] = *(const bf16x8*)(W4W + u * 512 + lane * 8);
    __syncthreads();                     // B1: all GEMM1 LDS reads done

    // h3 = ELU(acc) spilled into the SAME swizzled chunk layout
#pragma unroll
    for (int u = 0; u < 4; ++u) {
        const int ks = wave * 2 + (u >> 1);
        const int qw = (u & 1) * 2 + (l15 >> 3);
        const int j  = l15 & 7;
#pragma unroll
        for (int a = 0; a < 4; ++a)
#pragma unroll
            for (int r = 0; r < 4; ++r) {
                int rw = a * 16 + quad * 4 + r;
                int qp = qw ^ ((rw >> 1) & 3);
                h1s[ks * 2048 + rw * 32 + qp * 8 + j] = (bf16_t)elu(acc[a][u][r]);
            }
    }
    __syncthreads();                     // B2: h3 tile ready

    // ---- GEMM2: h3_tile @ W4b (streamed B) ----
#pragma unroll
    for (int a = 0; a < 4; ++a)
#pragma unroll
        for (int u = 0; u < 4; ++u) acc[a][u] = (f32x4){0.f, 0.f, 0.f, 0.f};
#pragma unroll
    for (int ks = 0; ks < 8; ++ks) {
        if (ks < 7) {
#pragma unroll
            for (int u = 0; u < 4; ++u)
                bnxt[u] = *(const bf16x8*)(W4W + (ks + 1) * 2048 + u * 512 + lane * 8);
        }
        bf16x8 afr[4];
#pragma unroll
        for (int a = 0; a < 4; ++a)
            afr[a] = *(const bf16x8*)&h1s[ks * 2048 + (a * 16 + l15) * 32 + xq8];
#pragma unroll
        for (int a = 0; a < 4; ++a)
#pragma unroll
            for (int u = 0; u < 4; ++u)
                acc[a][u] = __builtin_amdgcn_mfma_f32_16x16x32_bf16(afr[a], bcur[u], acc[a][u], 0, 0, 0);
#pragma unroll
        for (int u = 0; u < 4; ++u) bcur[u] = bnxt[u];
    }
    __syncthreads();                     // B3: all GEMM2 LDS reads done

    // epilogue: ELU + BN stats + write into swizzled layout
#pragma unroll
    for (int u = 0; u < 4; ++u) {
        const int col = wave * 64 + u * 16 + l15;
        const float bv = b2[col];
        const int ks = wave * 2 + (u >> 1);
        const int qw = (u & 1) * 2 + (l15 >> 3);
        const int j  = l15 & 7;
        float s = 0.f, q = 0.f;
#pragma unroll
        for (int a = 0; a < 4; ++a)
#pragma unroll
            for (int r = 0; r < 4; ++r) {
                float v = elu(acc[a][u][r] + bv);
                int rw = a * 16 + quad * 4 + r;
                int qp = qw ^ ((rw >> 1) & 3);
                h1s[ks * 2048 + rw * 32 + qp * 8 + j] = (bf16_t)v;
                s += v; q += v * v;
            }
        s += __shfl_xor(s, 16); s += __shfl_xor(s, 32);
        q += __shfl_xor(q, 16); q += __shfl_xor(q, 32);
        if (quad == 0) { atomicAdd(&sred[col], s); atomicAdd(&sred[256 + col], q); }
    }
    __syncthreads();                     // B4: outputs staged

    // coalesced store from swizzled layout
#pragma unroll
    for (int p = 0; p < 8; ++p) {
        int idx = p * 256 + tid;
        int r = idx >> 5, ch = idx & 31;
        *(uint4*)&out[(size_t)(m0 + r) * H + ch * 8] =
            *(const uint4*)&h1s[(ch >> 2) * 2048 + r * 32 + (((ch & 3) ^ ((r >> 1) & 3)) * 8)];
    }
    atomicAdd(&stats[tid],     sred[tid]);
    atomicAdd(&stats[H + tid], sred[256 + tid]);
}

// ---------------------------------------------------------------------------
// prep: all static weight prep in ONE kernel (block-index dispatch).
// All six 256x256 weights emit FRAGMENT ORDER. wtpq/wtrs ([512,256]) now
// also fragment order PER 256-COL HALF: dst = half*65536 + wv*16384 +
// ks*2048 + u*512 + lane*8 + j.
// ---------------------------------------------------------------------------
__global__ void prep(const float* __restrict__ w1a, bf16_t* __restrict__ wt1a,
                     const float* __restrict__ w1b, bf16_t* __restrict__ wt1b,
                     const float* __restrict__ w2b, bf16_t* __restrict__ wt2b,
                     const float* __restrict__ w3a, bf16_t* __restrict__ wt3a,
                     const float* __restrict__ w3b, bf16_t* __restrict__ wt3b,
                     const float* __restrict__ w4b, bf16_t* __restrict__ wt4b,
                     const float* __restrict__ w2a, bf16_t* __restrict__ wtpq,
                     const float* __restrict__ w4a, bf16_t* __restrict__ wtrs,
                     const float* __restrict__ b2a, float* __restrict__ biasPQ,
                     float* __restrict__ stats)
{
    int blk = blockIdx.x, tid = threadIdx.x;
    if (blk < 1536) {
        int grp = blk >> 8, lb = blk & 255;
        int idx = lb * 256 + tid;
        int k = idx >> 8, n = idx & 255;
        const float* w; bf16_t* wt;
        switch (grp) {
            case 0: w = w1a; wt = wt1a; break;
            case 1: w = w1b; wt = wt1b; break;
            case 2: w = w2b; wt = wt2b; break;
            case 3: w = w3a; wt = wt3a; break;
            case 4: w = w3b; wt = wt3b; break;
            default: w = w4b; wt = wt4b; break;
        }
        int wv = n >> 6, u = (n >> 4) & 3, l15 = n & 15;
        int ks = k >> 5, qd = (k >> 3) & 3, j = k & 7;
        wt[wv * 16384 + ks * 2048 + u * 512 + (qd * 16 + l15) * 8 + j] = (bf16_t)w[idx];
    } else if (blk < 2560) {
        int lb = blk - 1536;
        const float* w = (lb < 512) ? w2a : w4a;
        bf16_t* wt = (lb < 512) ? wtpq : wtrs;
        int c = lb & 511, k = tid;
        float v = (c < 256) ? w[k * 256 + c] : w[(256 + k) * 256 + (c - 256)];
        int half = c >> 8, n = c & 255;
        int wv = n >> 6, u = (n >> 4) & 3, l15 = n & 15;
        int ks = k >> 5, qd = (k >> 3) & 3, j = k & 7;
        wt[half * 65536 + wv * 16384 + ks * 2048 + u * 512 + (qd * 16 + l15) * 8 + j] = (bf16_t)v;
    } else if (blk == 2560) {
        biasPQ[tid] = b2a[tid];
        biasPQ[256 + tid] = 0.f;
    } else {
        for (int j = 0; j < 8; ++j) stats[j * 256 + tid] = 0.f;
    }
}

// prep2: blocks 0-255 build wsk in FRAGMENT ORDER (n=blk, k=tid); block 256
// builds bias_rs. sc2 computed in-kernel from raw stats2.
__global__ void prep2(const float* __restrict__ w4a, const float* __restrict__ stats2,
                      const float* __restrict__ g2, const float* __restrict__ be2,
                      const float* __restrict__ b4a, bf16_t* __restrict__ wt,
                      float* __restrict__ bias)
{
    __shared__ float sh2s[256];
    int blk = blockIdx.x, tid = threadIdx.x;
    float mean = stats2[tid] / (float)M_EDGE;
    float var  = stats2[256 + tid] / (float)M_EDGE - mean * mean;
    float scl  = g2[tid] * rsqrtf(var + BN_EPS);
    if (blk < 256) {
        int n = blk, k = tid;
        int wv = n >> 6, u = (n >> 4) & 3, l15 = n & 15;
        int ks = k >> 5, qd = (k >> 3) & 3, j = k & 7;
        wt[wv * 16384 + ks * 2048 + u * 512 + (qd * 16 + l15) * 8 + j] =
            (bf16_t)(w4a[(512 + tid) * 256 + blk] * scl);
    } else {
        sh2s[tid] = be2[tid] - mean * scl;
        __syncthreads();
        float acc = 0.f;
        for (int k = 0; k < 256; ++k)
            acc += sh2s[k] * w4a[(512 + k) * 256 + tid];
        bias[tid] = b4a[tid] + acc;
        bias[256 + tid] = 0.f;
    }
}

// edge2node w/ inline BN2 finalize
__global__ void edge2node(const bf16_t* __restrict__ x2, const float* __restrict__ stats2,
                          const float* __restrict__ g2, const float* __restrict__ be2,
                          bf16_t* __restrict__ inc)
{
    int bn = blockIdx.x, bb = bn >> 6, n = bn & 63;
    int g = threadIdx.x >> 5, t = threadIdx.x & 31;
    __shared__ float part[8][256];
    __shared__ float ss[512];
    {
        int c = threadIdx.x;
        float mean = stats2[c] / (float)M_EDGE;
        float var  = stats2[256 + c] / (float)M_EDGE - mean * mean;
        float scl  = g2[c] * rsqrtf(var + BN_EPS);
        ss[c]       = scl;
        ss[256 + c] = be2[c] - mean * scl;
    }
    const bf16_t* base = x2 + (size_t)bb * EB * H;
    float a[8] = {0.f,0.f,0.f,0.f,0.f,0.f,0.f,0.f};
    for (int i = g; i < NB; i += 8) {
        if (i == n) continue;
        int e = i * (NB - 1) + n - (n > i ? 1 : 0);
        bf16x8 v = *(const bf16x8*)&base[(size_t)e * H + t * 8];
#pragma unroll
        for (int j = 0; j < 8; ++j) a[j] += (float)v[j];
    }
#pragma unroll
    for (int j = 0; j < 8; ++j) part[g][t * 8 + j] = a[j];
    __syncthreads();
    int c = threadIdx.x;
    float s = 0.f;
#pragma unroll
    for (int g2i = 0; g2i < 8; ++g2i) s += part[g2i][c];
    inc[(size_t)bn * H + c] = (bf16_t)(s * (1.f / 64.f) * ss[c] + ss[256 + c] * (63.f / 64.f));
}

// fc w/ inline BN4 finalize
__global__ void fc_kernel(const bf16_t* __restrict__ x4, const float* __restrict__ stats4,
                          const float* __restrict__ g4, const float* __restrict__ be4,
                          const float* __restrict__ fcw, const float* __restrict__ fcb,
                          float* __restrict__ out)
{
    __shared__ float ss[512];
    {
        int c = threadIdx.x;
        float mean = stats4[c] / (float)M_EDGE;
        float var  = stats4[256 + c] / (float)M_EDGE - mean * mean;
        float scl  = g4[c] * rsqrtf(var + BN_EPS);
        ss[c]       = scl;
        ss[256 + c] = be4[c] - mean * scl;
    }
    __syncthreads();
    int row  = blockIdx.x * 8 + (threadIdx.x >> 5);
    int t    = threadIdx.x & 31;
    bf16x8 v8 = *(const bf16x8*)(x4 + (size_t)row * H + t * 8);
    float s0 = 0.f, s1 = 0.f;
#pragma unroll
    for (int j = 0; j < 8; ++j) {
        int c = t * 8 + j;
        float v = (float)v8[j] * ss[c] + ss[256 + c];
        s0 += v * fcw[c * 2];
        s1 += v * fcw[c * 2 + 1];
    }
#pragma unroll
    for (int off = 16; off; off >>= 1) {
        s0 += __shfl_down(s0, off, 32);
        s1 += __shfl_down(s1, off, 32);
    }
    if (t == 0) {
        out[(size_t)row * 2]     = s0 + fcb[0];
        out[(size_t)row * 2 + 1] = s1 + fcb[1];
    }
}

// ---------------------------------------------------------------------------
extern "C" void kernel_launch(void* const* d_in, const int* in_sizes, int n_in,
                              void* d_out, int out_size, void* d_ws, size_t ws_size,
                              hipStream_t stream)
{
    (void)in_sizes; (void)n_in; (void)out_size; (void)ws_size;
    const float* inp = (const float*)d_in[0];
    const float* w1a = (const float*)d_in[3];  const float* b1a = (const float*)d_in[4];
    const float* w1b = (const float*)d_in[5];  const float* b1b = (const float*)d_in[6];
    const float* g1  = (const float*)d_in[7];  const float* be1 = (const float*)d_in[8];
    const float* w2a = (const float*)d_in[9];  const float* b2a = (const float*)d_in[10];
    const float* w2b = (const float*)d_in[11]; const float* b2b = (const float*)d_in[12];
    const float* g2  = (const float*)d_in[13]; const float* be2 = (const float*)d_in[14];
    const float* w3a = (const float*)d_in[15]; const float* b3a = (const float*)d_in[16];
    const float* w3b = (const float*)d_in[17]; const float* b3b = (const float*)d_in[18];
    const float* g3  = (const float*)d_in[19]; const float* be3 = (const float*)d_in[20];
    const float* w4a = (const float*)d_in[21]; const float* b4a = (const float*)d_in[22];
    const float* w4b = (const float*)d_in[23]; const float* b4b = (const float*)d_in[24];
    const float* g4  = (const float*)d_in[25]; const float* be4 = (const float*)d_in[26];
    const float* fcw = (const float*)d_in[27]; const float* fcb = (const float*)d_in[28];

    char* p = (char*)d_ws;
    auto alloc = [&](size_t nbytes) { char* r = p; p += (nbytes + 255) & ~(size_t)255; return r; };

    bf16_t* wt1a = (bf16_t*)alloc(256 * 256 * 2);
    bf16_t* wt1b = (bf16_t*)alloc(256 * 256 * 2);
    bf16_t* wt2b = (bf16_t*)alloc(256 * 256 * 2);
    bf16_t* wt3a = (bf16_t*)alloc(256 * 256 * 2);
    bf16_t* wt3b = (bf16_t*)alloc(256 * 256 * 2);
    bf16_t* wt4b = (bf16_t*)alloc(256 * 256 * 2);
    bf16_t* wtpq = (bf16_t*)alloc(512 * 256 * 2);
    bf16_t* wtrs = (bf16_t*)alloc(512 * 256 * 2);
    bf16_t* wtsk = (bf16_t*)alloc(256 * 256 * 2);
    float*  biasPQ = (float*)alloc(512 * sizeof(float));
    float*  biasRS = (float*)alloc(512 * sizeof(float));
    float*  stats  = (float*)alloc(4 * 512 * sizeof(float));
    bf16_t* x1   = (bf16_t*)alloc((size_t)M_NODE * H * 2);
    bf16_t* incb = (bf16_t*)alloc((size_t)M_NODE * H * 2);
    bf16_t* x3   = (bf16_t*)alloc((size_t)M_NODE * H * 2);
    float*  PQ   = (float*)alloc((size_t)M_NODE * 512 * sizeof(float));
    float*  RS   = (float*)alloc((size_t)M_NODE * 512 * sizeof(float));
    bf16_t* h2   = (bf16_t*)alloc((size_t)M_EDGE * H * 2);
    bf16_t* h4   = (bf16_t*)alloc((size_t)M_EDGE * H * 2);

    // all static prep in one launch
    prep<<<2562, 256, 0, stream>>>(w1a, wt1a, w1b, wt1b, w2b, wt2b, w3a, wt3a,
                                   w3b, wt3b, w4b, wt4b, w2a, wtpq, w4a, wtrs,
                                   b2a, biasPQ, stats);

    // MLP1 (nodes, streamed B, M-tile 32) -> x1, stats1
    fused_mlp<true ><<<M_NODE / 32, 256, 0, stream>>>(inp, wt1a, b1a, wt1b, b1b, x1, stats + 0);

    // PQ = BN1(x1) @ [W2a_s | W2a_r] + [b2a|0]  (streamed B, M-tile 32)
    { dim3 g(M_NODE / 32, 2);
      node_gemm<<<g, 256, 0, stream>>>(x1, stats + 0, g1, be1, (float)M_NODE, wtpq, biasPQ, PQ); }

    // MLP2 (edges, streamed fragment-order B + swizzled LDS, T=1) -> h2, stats2
    m2_kernel<<<M_EDGE / 64, 256, 0, stream>>>(PQ, wt2b, b2b, h2, stats + 512);

    // edge2node (BN2 finalize+fold inline) + MLP3 (nodes, streamed B, M-tile 32)
    edge2node<<<M_NODE, 256, 0, stream>>>(h2, stats + 512, g2, be2, incb);
    fused_mlp<false><<<M_NODE / 32, 256, 0, stream>>>(incb, wt3a, b3a, wt3b, b3b, x3, stats + 1024);

    // BN2-folded skip weight (fragment order) + RS bias
    prep2<<<257, 256, 0, stream>>>(w4a, stats + 512, g2, be2, b4a, wtsk, biasRS);
    // RS = BN3(x3) @ [W4a_s | W4a_r] + biasRS  (streamed B, M-tile 32)
    { dim3 g(M_NODE / 32, 2);
      node_gemm<<<g, 256, 0, stream>>>(x3, stats + 1024, g3, be3, (float)M_NODE, wtrs, biasRS, RS); }

    // MLP4 (edges, streamed B + RS-init-acc + async swizzled stage) -> h4, stats4
    m4_kernel<<<M_EDGE / 64, 256, 0, stream>>>(h2, wtsk, RS, wt4b, b4b, h4, stats + 1536);

    // final fc with BN4 finalize+fold inline, fp32 output
    fc_kernel<<<M_EDGE / 8, 256, 0, stream>>>(h4, stats + 1536, g4, be4, fcw, fcb, (float*)d_out);
}

// Round 14
// 336.810 us; speedup vs baseline: 1.0474x; 1.0095x over previous
//
#include <hip/hip_runtime.h>

typedef __bf16 bf16_t;
typedef __bf16 bf16x8 __attribute__((ext_vector_type(8)));
typedef float  f32x4  __attribute__((ext_vector_type(4)));

#define NB    64
#define EB    4032            // NB*(NB-1)
#define BATCH 32
#define H     256
#define M_EDGE (BATCH*EB)     // 129024
#define M_NODE (BATCH*NB)     // 2048
#define BN_EPS 1e-5f

__device__ __forceinline__ void load_lds16(const void* g, void* l) {
    __builtin_amdgcn_global_load_lds(
        (const __attribute__((address_space(1))) unsigned int*)g,
        (__attribute__((address_space(3))) unsigned int*)l, 16, 0, 0);
}
// fast ELU: v_exp_f32 (+mul) instead of ~35-inst expm1f; bf16-rounding dwarfs the error
__device__ __forceinline__ float elu(float v) { return v > 0.f ? v : __expf(v) - 1.f; }

// ---------------------------------------------------------------------------
// Fused 2-layer node MLP, STREAMED-B, M-TILE 32 (R13 winner).
// ---------------------------------------------------------------------------
template<bool AF32>
__global__ __launch_bounds__(256, 3)
void fused_mlp(const void* __restrict__ A0v,
               const bf16_t* __restrict__ W1f, const float* __restrict__ b1,
               const bf16_t* __restrict__ W2f, const float* __restrict__ b2,
               bf16_t* __restrict__ out, float* __restrict__ stats)
{
    const int m0 = blockIdx.x * 32;
    const int tid = threadIdx.x, wave = tid >> 6, lane = tid & 63;
    const int l15 = lane & 15, quad = lane >> 4;
    const int row = tid >> 3;            // 0..31
    const int c0 = (tid & 7) * 32;       // 8 threads/row x 32 cols

    __shared__ bf16_t h1s[32 * 264];
    __shared__ float  sred[512];

    sred[tid] = 0.f; sred[256 + tid] = 0.f;

    // stage A tile (32x256) into padded LDS
    if (AF32) {
        const float* af = (const float*)A0v + (size_t)(m0 + row) * 256 + c0;
#pragma unroll
        for (int j = 0; j < 4; ++j) {
            float4 lo = *(const float4*)(af + j * 8);
            float4 hi = *(const float4*)(af + j * 8 + 4);
            bf16x8 v;
            v[0]=(bf16_t)lo.x; v[1]=(bf16_t)lo.y; v[2]=(bf16_t)lo.z; v[3]=(bf16_t)lo.w;
            v[4]=(bf16_t)hi.x; v[5]=(bf16_t)hi.y; v[6]=(bf16_t)hi.z; v[7]=(bf16_t)hi.w;
            *(bf16x8*)&h1s[row * 264 + c0 + j * 8] = v;
        }
    } else {
        const bf16_t* src = (const bf16_t*)A0v + (size_t)(m0 + row) * 256 + c0;
#pragma unroll
        for (int j = 0; j < 4; ++j)
            *(bf16x8*)&h1s[row * 264 + c0 + j * 8] = *(const bf16x8*)(src + j * 8);
    }

    // per-wave fragment-order bases
    const bf16_t* W1W = W1f + (size_t)wave * 16384;
    const bf16_t* W2W = W2f + (size_t)wave * 16384;

    bf16x8 bcur[4], bnxt[4];
#pragma unroll
    for (int u = 0; u < 4; ++u)
        bcur[u] = *(const bf16x8*)(W1W + u * 512 + lane * 8);
    __syncthreads();                     // A tile ready (B ks=0 in flight)

    f32x4 acc[2][4];
#pragma unroll
    for (int a = 0; a < 2; ++a)
#pragma unroll
        for (int u = 0; u < 4; ++u) acc[a][u] = (f32x4){0.f, 0.f, 0.f, 0.f};

    // ---- layer 1: A @ W1 (streamed B, barrier-free) ----
#pragma unroll
    for (int ks = 0; ks < 8; ++ks) {
        if (ks < 7) {
#pragma unroll
            for (int u = 0; u < 4; ++u)
                bnxt[u] = *(const bf16x8*)(W1W + (ks + 1) * 2048 + u * 512 + lane * 8);
        }
        bf16x8 afr[2];
#pragma unroll
        for (int a = 0; a < 2; ++a)
            afr[a] = *(const bf16x8*)&h1s[(a * 16 + l15) * 264 + ks * 32 + quad * 8];
#pragma unroll
        for (int a = 0; a < 2; ++a)
#pragma unroll
            for (int u = 0; u < 4; ++u)
                acc[a][u] = __builtin_amdgcn_mfma_f32_16x16x32_bf16(afr[a], bcur[u], acc[a][u], 0, 0, 0);
#pragma unroll
        for (int u = 0; u < 4; ++u) bcur[u] = bnxt[u];
    }

    // prefetch layer-2 ks=0 (hides under h1 spill)
#pragma unroll
    for (int u = 0; u < 4; ++u)
        bcur[u] = *(const bf16x8*)(W2W + u * 512 + lane * 8);
    __syncthreads();                     // B1: all layer-1 LDS reads done

    // h1 = ELU(acc + b1), spilled to LDS row-major
#pragma unroll
    for (int u = 0; u < 4; ++u) {
        int   col = wave * 64 + u * 16 + l15;
        float bv  = b1[col];
#pragma unroll
        for (int a = 0; a < 2; ++a)
#pragma unroll
            for (int r = 0; r < 4; ++r)
                h1s[(a * 16 + quad * 4 + r) * 264 + col] = (bf16_t)elu(acc[a][u][r] + bv);
    }
    __syncthreads();                     // B2: h1 visible

    // ---- layer 2: h1 @ W2 (streamed B, barrier-free) ----
#pragma unroll
    for (int a = 0; a < 2; ++a)
#pragma unroll
        for (int u = 0; u < 4; ++u) acc[a][u] = (f32x4){0.f, 0.f, 0.f, 0.f};
#pragma unroll
    for (int ks = 0; ks < 8; ++ks) {
        if (ks < 7) {
#pragma unroll
            for (int u = 0; u < 4; ++u)
                bnxt[u] = *(const bf16x8*)(W2W + (ks + 1) * 2048 + u * 512 + lane * 8);
        }
        bf16x8 afr[2];
#pragma unroll
        for (int a = 0; a < 2; ++a)
            afr[a] = *(const bf16x8*)&h1s[(a * 16 + l15) * 264 + ks * 32 + quad * 8];
#pragma unroll
        for (int a = 0; a < 2; ++a)
#pragma unroll
            for (int u = 0; u < 4; ++u)
                acc[a][u] = __builtin_amdgcn_mfma_f32_16x16x32_bf16(afr[a], bcur[u], acc[a][u], 0, 0, 0);
#pragma unroll
        for (int u = 0; u < 4; ++u) bcur[u] = bnxt[u];
    }
    __syncthreads();                     // B3: all layer-2 LDS reads done

    // epilogue: ELU + BN stats + bf16 write-back
#pragma unroll
    for (int u = 0; u < 4; ++u) {
        int   col = wave * 64 + u * 16 + l15;
        float bv  = b2[col];
        float s = 0.f, q = 0.f;
#pragma unroll
        for (int a = 0; a < 2; ++a)
#pragma unroll
            for (int r = 0; r < 4; ++r) {
                float v = elu(acc[a][u][r] + bv);
                h1s[(a * 16 + quad * 4 + r) * 264 + col] = (bf16_t)v;
                s += v; q += v * v;
            }
        s += __shfl_xor(s, 16); s += __shfl_xor(s, 32);
        q += __shfl_xor(q, 16); q += __shfl_xor(q, 32);
        if (quad == 0) { atomicAdd(&sred[col], s); atomicAdd(&sred[256 + col], q); }
    }
    __syncthreads();                     // B4: outputs staged

#pragma unroll
    for (int p = 0; p < 4; ++p) {
        int idx = p * 256 + tid;
        int r = idx >> 5, ch = idx & 31;
        *(uint4*)&out[(size_t)(m0 + r) * H + ch * 8] = *(const uint4*)&h1s[r * 264 + ch * 8];
    }
    atomicAdd(&stats[tid],     sred[tid]);
    atomicAdd(&stats[H + tid], sred[256 + tid]);
}

// ---------------------------------------------------------------------------
// Node GEMM (R13 structure, R14: templated output type). BF16OUT=true for PQ
// (halves store traffic; PQ 4MB->2MB so random Q-row gathers are L2-resident);
// false (f32) for RS (m4's f32 acc-init numerics untouched).
// ---------------------------------------------------------------------------
template<bool BF16OUT>
__global__ __launch_bounds__(256, 3)
void node_gemm(const bf16_t* __restrict__ A, const float* __restrict__ statsIn,
               const float* __restrict__ g, const float* __restrict__ beta, float Mcnt,
               const bf16_t* __restrict__ Wf, const float* __restrict__ bias,
               void* __restrict__ outv)
{
    const int m0 = blockIdx.x * 32;
    const int nb = blockIdx.y * 256;
    const int tid = threadIdx.x, wave = tid >> 6, lane = tid & 63;
    const int l15 = lane & 15, quad = lane >> 4;
    const int row = tid >> 3;            // 0..31
    const int c0 = (tid & 7) * 32;
    const int xq8 = (quad ^ ((l15 >> 1) & 3)) * 8;

    __shared__ bf16_t As[8 * 1024];      // 8 ks-chunks x [32][32], swizzled
    __shared__ float  ss[512];           // scale | shift

    {   // BN finalize inline
        float mean = statsIn[tid] / Mcnt;
        float var  = statsIn[256 + tid] / Mcnt - mean * mean;
        float scl  = g[tid] * rsqrtf(var + BN_EPS);
        ss[tid]       = scl;
        ss[256 + tid] = beta[tid] - mean * scl;
    }
    __syncthreads();                     // B0: ss ready

    // BN-folded A staging into swizzled chunks (VGPR path)
    {
        const bf16_t* Ar = A + (size_t)(m0 + row) * 256 + c0;
        const int rs = (row >> 1) & 3;
#pragma unroll
        for (int j = 0; j < 4; ++j) {
            int c = c0 + j * 8;
            bf16x8 v = *(const bf16x8*)(Ar + j * 8);
            bf16x8 w;
#pragma unroll
            for (int e = 0; e < 8; ++e)
                w[e] = (bf16_t)((float)v[e] * ss[c + e] + ss[256 + c + e]);
            *(bf16x8*)&As[(c >> 5) * 1024 + row * 32 + ((((c >> 3) & 3) ^ rs) * 8)] = w;
        }
    }

    // per-half, per-wave fragment-order weight base
    const bf16_t* WW = Wf + (size_t)blockIdx.y * 65536 + (size_t)wave * 16384;
    bf16x8 bcur[4], bnxt[4];
#pragma unroll
    for (int u = 0; u < 4; ++u)
        bcur[u] = *(const bf16x8*)(WW + u * 512 + lane * 8);
    __syncthreads();                     // B1: A staged

    f32x4 acc[2][4];
#pragma unroll
    for (int a = 0; a < 2; ++a)
#pragma unroll
        for (int u = 0; u < 4; ++u) acc[a][u] = (f32x4){0.f, 0.f, 0.f, 0.f};

    // ---- GEMM (streamed B, barrier-free) ----
#pragma unroll
    for (int ks = 0; ks < 8; ++ks) {
        if (ks < 7) {
#pragma unroll
            for (int u = 0; u < 4; ++u)
                bnxt[u] = *(const bf16x8*)(WW + (ks + 1) * 2048 + u * 512 + lane * 8);
        }
        bf16x8 afr[2];
#pragma unroll
        for (int a = 0; a < 2; ++a)
            afr[a] = *(const bf16x8*)&As[ks * 1024 + (a * 16 + l15) * 32 + xq8];
#pragma unroll
        for (int a = 0; a < 2; ++a)
#pragma unroll
            for (int u = 0; u < 4; ++u)
                acc[a][u] = __builtin_amdgcn_mfma_f32_16x16x32_bf16(afr[a], bcur[u], acc[a][u], 0, 0, 0);
#pragma unroll
        for (int u = 0; u < 4; ++u) bcur[u] = bnxt[u];
    }

    // epilogue: + bias, direct global write (no barrier needed)
#pragma unroll
    for (int u = 0; u < 4; ++u) {
        int col = nb + wave * 64 + u * 16 + l15;
        float bv = bias[col];
#pragma unroll
        for (int a = 0; a < 2; ++a)
#pragma unroll
            for (int r = 0; r < 4; ++r) {
                float v = acc[a][u][r] + bv;
                size_t off = (size_t)(m0 + a * 16 + quad * 4 + r) * 512 + col;
                if (BF16OUT) ((bf16_t*)outv)[off] = (bf16_t)v;
                else         ((float*)outv)[off]  = v;
            }
    }
}

// ---------------------------------------------------------------------------
// MLP2 (R14): R12 structure; PQ now BF16 (16 gather loads/thread instead of
// 32; PQ 2MB L2-resident). computeA writes ELU(P+Q) straight into the
// XOR-swizzled chunk layout; block-uniform edge decomposition; 3 barriers.
// ---------------------------------------------------------------------------
__global__ __launch_bounds__(256, 3)
void m2_kernel(const bf16_t* __restrict__ PQ, const bf16_t* __restrict__ W2f,
               const float* __restrict__ b2, bf16_t* __restrict__ out,
               float* __restrict__ stats)
{
    const int m0 = blockIdx.x * 64;
    const int tid = threadIdx.x, wave = tid >> 6, lane = tid & 63;
    const int l15 = lane & 15, quad = lane >> 4;
    const int row = tid >> 2;
    const int c0 = (tid & 3) * 64;
    const int xq8 = (quad ^ ((l15 >> 1) & 3)) * 8;

    __shared__ bf16_t h1s[8 * 2048];     // 8 ks-chunks x [64 rows][32 cols], swizzled
    __shared__ float  sred[512];

    sred[tid] = 0.f; sred[256 + tid] = 0.f;

    // block-uniform edge decomposition (SALU)
    const int bb  = m0 / EB;
    const int e0  = m0 - bb * EB;
    const int sn0 = e0 / (NB - 1);
    const int rr0 = e0 - sn0 * (NB - 1);

    // computeA: ELU(P+Q) written directly into the swizzled chunk layout
    {
        int t  = rr0 + row;
        int wrap = (t >= NB - 1) ? 1 : 0;
        int sn = sn0 + wrap;
        int rr = t - (wrap ? (NB - 1) : 0);
        int rc = rr + (rr >= sn ? 1 : 0);
        const bf16_t* Prow = PQ + (size_t)(bb * NB + sn) * 512;
        const bf16_t* Qrow = PQ + (size_t)(bb * NB + rc) * 512 + 256;
        const int rs = ((row >> 1) & 3);
#pragma unroll
        for (int j = 0; j < 8; ++j) {
            int c = c0 + j * 8;
            bf16x8 pv = *(const bf16x8*)(Prow + c);
            bf16x8 qv = *(const bf16x8*)(Qrow + c);
            bf16x8 v;
#pragma unroll
            for (int e = 0; e < 8; ++e)
                v[e] = (bf16_t)elu((float)pv[e] + (float)qv[e]);
            *(bf16x8*)&h1s[(c >> 5) * 2048 + row * 32 + ((((c >> 3) & 3) ^ rs) * 8)] = v;
        }
    }

    // stream B ks=0 (in flight across the barrier)
    const bf16_t* W2W = W2f + (size_t)wave * 16384;
    bf16x8 bcur[4], bnxt[4];
#pragma unroll
    for (int u = 0; u < 4; ++u)
        bcur[u] = *(const bf16x8*)(W2W + u * 512 + lane * 8);
    __syncthreads();                     // B0: A tile ready

    f32x4 acc[4][4];
#pragma unroll
    for (int a = 0; a < 4; ++a)
#pragma unroll
        for (int u = 0; u < 4; ++u) acc[a][u] = (f32x4){0.f, 0.f, 0.f, 0.f};

    // ---- GEMM: A @ W2b (streamed B, barrier-free) ----
#pragma unroll
    for (int ks = 0; ks < 8; ++ks) {
        if (ks < 7) {
#pragma unroll
            for (int u = 0; u < 4; ++u)
                bnxt[u] = *(const bf16x8*)(W2W + (ks + 1) * 2048 + u * 512 + lane * 8);
        }
        bf16x8 afr[4];
#pragma unroll
        for (int a = 0; a < 4; ++a)
            afr[a] = *(const bf16x8*)&h1s[ks * 2048 + (a * 16 + l15) * 32 + xq8];
#pragma unroll
        for (int a = 0; a < 4; ++a)
#pragma unroll
            for (int u = 0; u < 4; ++u)
                acc[a][u] = __builtin_amdgcn_mfma_f32_16x16x32_bf16(afr[a], bcur[u], acc[a][u], 0, 0, 0);
#pragma unroll
        for (int u = 0; u < 4; ++u) bcur[u] = bnxt[u];
    }
    __syncthreads();                     // B1: all GEMM LDS reads done

    // epilogue: ELU + BN stats + write into swizzled layout
#pragma unroll
    for (int u = 0; u < 4; ++u) {
        const int col = wave * 64 + u * 16 + l15;
        const float bv = b2[col];
        const int ks = wave * 2 + (u >> 1);
        const int qw = (u & 1) * 2 + (l15 >> 3);
        const int j  = l15 & 7;
        float s = 0.f, q = 0.f;
#pragma unroll
        for (int a = 0; a < 4; ++a)
#pragma unroll
            for (int r = 0; r < 4; ++r) {
                float v = elu(acc[a][u][r] + bv);
                int rw = a * 16 + quad * 4 + r;
                int qp = qw ^ ((rw >> 1) & 3);
                h1s[ks * 2048 + rw * 32 + qp * 8 + j] = (bf16_t)v;
                s += v; q += v * v;
            }
        s += __shfl_xor(s, 16); s += __shfl_xor(s, 32);
        q += __shfl_xor(q, 16); q += __shfl_xor(q, 32);
        if (quad == 0) { atomicAdd(&sred[col], s); atomicAdd(&sred[256 + col], q); }
    }
    __syncthreads();                     // B2: outputs staged

    // coalesced store from swizzled layout
#pragma unroll
    for (int p = 0; p < 8; ++p) {
        int idx = p * 256 + tid;
        int r = idx >> 5, ch = idx & 31;
        *(uint4*)&out[(size_t)(m0 + r) * H + ch * 8] =
            *(const uint4*)&h1s[(ch >> 2) * 2048 + r * 32 + (((ch & 3) ^ ((r >> 1) & 3)) * 8)];
    }
    atomicAdd(&stats[tid],     sred[tid]);
    atomicAdd(&stats[H + tid], sred[256 + tid]);
}

// ---------------------------------------------------------------------------
// MLP4 fused (R11 winner): streamed fragment-order B + RS-init-acc + async
// swizzled-chunk staging; RS indices block-uniform; 5 barriers.
// ---------------------------------------------------------------------------
__global__ __launch_bounds__(256, 3)
void m4_kernel(const bf16_t* __restrict__ h2, const bf16_t* __restrict__ Wskf,
               const float* __restrict__ RS, const bf16_t* __restrict__ W4f,
               const float* __restrict__ b2, bf16_t* __restrict__ out,
               float* __restrict__ stats)
{
    const int m0 = blockIdx.x * 64;
    const int tid = threadIdx.x, wave = tid >> 6, lane = tid & 63;
    const int l15 = lane & 15, quad = lane >> 4;
    const int row = tid >> 2;
    const int cx8 = (((tid & 3) ^ ((tid >> 3) & 3))) * 8;
    const int xq8 = (quad ^ ((l15 >> 1) & 3)) * 8;

    __shared__ bf16_t h1s[8 * 2048];     // 8 ks-chunks x [64 rows][32 cols], swizzled
    __shared__ float  sred[512];

    sred[tid] = 0.f; sred[256 + tid] = 0.f;

    // block-uniform edge decomposition (SALU): bb, e0, sn0, rr0
    const int bb  = m0 / EB;
    const int e0  = m0 - bb * EB;
    const int sn0 = e0 / (NB - 1);
    const int rr0 = e0 - sn0 * (NB - 1);
    const float* RSb = RS + (size_t)(bb * NB) * 512;

    // async-stage full h2 tile: 8 x global_load_lds per thread (no reg roundtrip)
#pragma unroll
    for (int ks = 0; ks < 8; ++ks)
        load_lds16(h2 + (size_t)(m0 + row) * 256 + ks * 32 + cx8,
                   h1s + ks * 2048 + wave * 512);

    // acc init = S + R, loads issued pre-barrier (latency hides under stage)
    f32x4 acc[4][4];
#pragma unroll
    for (int a = 0; a < 4; ++a)
#pragma unroll
        for (int r = 0; r < 4; ++r) {
            int ro = a * 16 + quad * 4 + r;
            int t  = rr0 + ro;
            int wrap = (t >= NB - 1) ? 1 : 0;
            int sn = sn0 + wrap;
            int rr = t - (wrap ? (NB - 1) : 0);
            int rc = rr + (rr >= sn ? 1 : 0);
            const float* Srow = RSb + (size_t)sn * 512;
            const float* Rrow = RSb + (size_t)rc * 512 + 256;
#pragma unroll
            for (int u = 0; u < 4; ++u) {
                int co = wave * 64 + u * 16 + l15;
                acc[a][u][r] = Srow[co] + Rrow[co];
            }
        }

    // per-wave fragment-order weight bases
    const bf16_t* WskW = Wskf + (size_t)wave * 16384;
    const bf16_t* W4W  = W4f  + (size_t)wave * 16384;

    bf16x8 bcur[4], bnxt[4];
#pragma unroll
    for (int u = 0; u < 4; ++u)
        bcur[u] = *(const bf16x8*)(WskW + u * 512 + lane * 8);
    __syncthreads();                     // B0: stage drained, RS in acc

    // ---- GEMM1: h2_tile @ Wsk (streamed B; acc carries S+R) ----
#pragma unroll
    for (int ks = 0; ks < 8; ++ks) {
        if (ks < 7) {
#pragma unroll
            for (int u = 0; u < 4; ++u)
                bnxt[u] = *(const bf16x8*)(WskW + (ks + 1) * 2048 + u * 512 + lane * 8);
        }
        bf16x8 afr[4];
#pragma unroll
        for (int a = 0; a < 4; ++a)
            afr[a] = *(const bf16x8*)&h1s[ks * 2048 + (a * 16 + l15) * 32 + xq8];
#pragma unroll
        for (int a = 0; a < 4; ++a)
#pragma unroll
            for (int u = 0; u < 4; ++u)
                acc[a][u] = __builtin_amdgcn_mfma_f32_16x16x32_bf16(afr[a], bcur[u], acc[a][u], 0, 0, 0);
#pragma unroll
        for (int u = 0; u < 4; ++u) bcur[u] = bnxt[u];
    }

    // prefetch GEMM2 ks=0 (hides under h3 spill)
#pragma unroll
    for (int u = 0; u < 4; ++u)
        bcur[u] = *(const bf16x8*)(W4W + u * 512 + lane * 8);
    __syncthreads();                     // B1: all GEMM1 LDS reads done

    // h3 = ELU(acc) spilled into the SAME swizzled chunk layout
#pragma unroll
    for (int u = 0; u < 4; ++u) {
        const int ks = wave * 2 + (u >> 1);
        const int qw = (u & 1) * 2 + (l15 >> 3);
        const int j  = l15 & 7;
#pragma unroll
        for (int a = 0; a < 4; ++a)
#pragma unroll
            for (int r = 0; r < 4; ++r) {
                int rw = a * 16 + quad * 4 + r;
                int qp = qw ^ ((rw >> 1) & 3);
                h1s[ks * 2048 + rw * 32 + qp * 8 + j] = (bf16_t)elu(acc[a][u][r]);
            }
    }
    __syncthreads();                     // B2: h3 tile ready

    // ---- GEMM2: h3_tile @ W4b (streamed B) ----
#pragma unroll
    for (int a = 0; a < 4; ++a)
#pragma unroll
        for (int u = 0; u < 4; ++u) acc[a][u] = (f32x4){0.f, 0.f, 0.f, 0.f};
#pragma unroll
    for (int ks = 0; ks < 8; ++ks) {
        if (ks < 7) {
#pragma unroll
            for (int u = 0; u < 4; ++u)
                bnxt[u] = *(const bf16x8*)(W4W + (ks + 1) * 2048 + u * 512 + lane * 8);
        }
        bf16x8 afr[4];
#pragma unroll
        for (int a = 0; a < 4; ++a)
            afr[a] = *(const bf16x8*)&h1s[ks * 2048 + (a * 16 + l15) * 32 + xq8];
#pragma unroll
        for (int a = 0; a < 4; ++a)
#pragma unroll
            for (int u = 0; u < 4; ++u)
                acc[a][u] = __builtin_amdgcn_mfma_f32_16x16x32_bf16(afr[a], bcur[u], acc[a][u], 0, 0, 0);
#pragma unroll
        for (int u = 0; u < 4; ++u) bcur[u] = bnxt[u];
    }
    __syncthreads();                     // B3: all GEMM2 LDS reads done

    // epilogue: ELU + BN stats + write into swizzled layout
#pragma unroll
    for (int u = 0; u < 4; ++u) {
        const int col = wave * 64 + u * 16 + l15;
        const float bv = b2[col];
        const int ks = wave * 2 + (u >> 1);
        const int qw = (u & 1) * 2 + (l15 >> 3);
        const int j  = l15 & 7;
        float s = 0.f, q = 0.f;
#pragma unroll
        for (int a = 0; a < 4; ++a)
#pragma unroll
            for (int r = 0; r < 4; ++r) {
                float v = elu(acc[a][u][r] + bv);
                int rw = a * 16 + quad * 4 + r;
                int qp = qw ^ ((rw >> 1) & 3);
                h1s[ks * 2048 + rw * 32 + qp * 8 + j] = (bf16_t)v;
                s += v; q += v * v;
            }
        s += __shfl_xor(s, 16); s += __shfl_xor(s, 32);
        q += __shfl_xor(q, 16); q += __shfl_xor(q, 32);
        if (quad == 0) { atomicAdd(&sred[col], s); atomicAdd(&sred[256 + col], q); }
    }
    __syncthreads();                     // B4: outputs staged

    // coalesced store from swizzled layout
#pragma unroll
    for (int p = 0; p < 8; ++p) {
        int idx = p * 256 + tid;
        int r = idx >> 5, ch = idx & 31;
        *(uint4*)&out[(size_t)(m0 + r) * H + ch * 8] =
            *(const uint4*)&h1s[(ch >> 2) * 2048 + r * 32 + (((ch & 3) ^ ((r >> 1) & 3)) * 8)];
    }
    atomicAdd(&stats[tid],     sred[tid]);
    atomicAdd(&stats[H + tid], sred[256 + tid]);
}

// ---------------------------------------------------------------------------
// prep: all static weight prep in ONE kernel (block-index dispatch).
// All six 256x256 weights emit FRAGMENT ORDER. wtpq/wtrs ([512,256]) in
// fragment order PER 256-COL HALF: dst = half*65536 + wv*16384 + ks*2048 +
// u*512 + lane*8 + j.
// ---------------------------------------------------------------------------
__global__ void prep(const float* __restrict__ w1a, bf16_t* __restrict__ wt1a,
                     const float* __restrict__ w1b, bf16_t* __restrict__ wt1b,
                     const float* __restrict__ w2b, bf16_t* __restrict__ wt2b,
                     const float* __restrict__ w3a, bf16_t* __restrict__ wt3a,
                     const float* __restrict__ w3b, bf16_t* __restrict__ wt3b,
                     const float* __restrict__ w4b, bf16_t* __restrict__ wt4b,
                     const float* __restrict__ w2a, bf16_t* __restrict__ wtpq,
                     const float* __restrict__ w4a, bf16_t* __restrict__ wtrs,
                     const float* __restrict__ b2a, float* __restrict__ biasPQ,
                     float* __restrict__ stats)
{
    int blk = blockIdx.x, tid = threadIdx.x;
    if (blk < 1536) {
        int grp = blk >> 8, lb = blk & 255;
        int idx = lb * 256 + tid;
        int k = idx >> 8, n = idx & 255;
        const float* w; bf16_t* wt;
        switch (grp) {
            case 0: w = w1a; wt = wt1a; break;
            case 1: w = w1b; wt = wt1b; break;
            case 2: w = w2b; wt = wt2b; break;
            case 3: w = w3a; wt = wt3a; break;
            case 4: w = w3b; wt = wt3b; break;
            default: w = w4b; wt = wt4b; break;
        }
        int wv = n >> 6, u = (n >> 4) & 3, l15 = n & 15;
        int ks = k >> 5, qd = (k >> 3) & 3, j = k & 7;
        wt[wv * 16384 + ks * 2048 + u * 512 + (qd * 16 + l15) * 8 + j] = (bf16_t)w[idx];
    } else if (blk < 2560) {
        int lb = blk - 1536;
        const float* w = (lb < 512) ? w2a : w4a;
        bf16_t* wt = (lb < 512) ? wtpq : wtrs;
        int c = lb & 511, k = tid;
        float v = (c < 256) ? w[k * 256 + c] : w[(256 + k) * 256 + (c - 256)];
        int half = c >> 8, n = c & 255;
        int wv = n >> 6, u = (n >> 4) & 3, l15 = n & 15;
        int ks = k >> 5, qd = (k >> 3) & 3, j = k & 7;
        wt[half * 65536 + wv * 16384 + ks * 2048 + u * 512 + (qd * 16 + l15) * 8 + j] = (bf16_t)v;
    } else if (blk == 2560) {
        biasPQ[tid] = b2a[tid];
        biasPQ[256 + tid] = 0.f;
    } else {
        for (int j = 0; j < 8; ++j) stats[j * 256 + tid] = 0.f;
    }
}

// prep2: blocks 0-255 build wsk in FRAGMENT ORDER (n=blk, k=tid); block 256
// builds bias_rs. sc2 computed in-kernel from raw stats2.
__global__ void prep2(const float* __restrict__ w4a, const float* __restrict__ stats2,
                      const float* __restrict__ g2, const float* __restrict__ be2,
                      const float* __restrict__ b4a, bf16_t* __restrict__ wt,
                      float* __restrict__ bias)
{
    __shared__ float sh2s[256];
    int blk = blockIdx.x, tid = threadIdx.x;
    float mean = stats2[tid] / (float)M_EDGE;
    float var  = stats2[256 + tid] / (float)M_EDGE - mean * mean;
    float scl  = g2[tid] * rsqrtf(var + BN_EPS);
    if (blk < 256) {
        int n = blk, k = tid;
        int wv = n >> 6, u = (n >> 4) & 3, l15 = n & 15;
        int ks = k >> 5, qd = (k >> 3) & 3, j = k & 7;
        wt[wv * 16384 + ks * 2048 + u * 512 + (qd * 16 + l15) * 8 + j] =
            (bf16_t)(w4a[(512 + tid) * 256 + blk] * scl);
    } else {
        sh2s[tid] = be2[tid] - mean * scl;
        __syncthreads();
        float acc = 0.f;
        for (int k = 0; k < 256; ++k)
            acc += sh2s[k] * w4a[(512 + k) * 256 + tid];
        bias[tid] = b4a[tid] + acc;
        bias[256 + tid] = 0.f;
    }
}

// edge2node w/ inline BN2 finalize
__global__ void edge2node(const bf16_t* __restrict__ x2, const float* __restrict__ stats2,
                          const float* __restrict__ g2, const float* __restrict__ be2,
                          bf16_t* __restrict__ inc)
{
    int bn = blockIdx.x, bb = bn >> 6, n = bn & 63;
    int g = threadIdx.x >> 5, t = threadIdx.x & 31;
    __shared__ float part[8][256];
    __shared__ float ss[512];
    {
        int c = threadIdx.x;
        float mean = stats2[c] / (float)M_EDGE;
        float var  = stats2[256 + c] / (float)M_EDGE - mean * mean;
        float scl  = g2[c] * rsqrtf(var + BN_EPS);
        ss[c]       = scl;
        ss[256 + c] = be2[c] - mean * scl;
    }
    const bf16_t* base = x2 + (size_t)bb * EB * H;
    float a[8] = {0.f,0.f,0.f,0.f,0.f,0.f,0.f,0.f};
    for (int i = g; i < NB; i += 8) {
        if (i == n) continue;
        int e = i * (NB - 1) + n - (n > i ? 1 : 0);
        bf16x8 v = *(const bf16x8*)&base[(size_t)e * H + t * 8];
#pragma unroll
        for (int j = 0; j < 8; ++j) a[j] += (float)v[j];
    }
#pragma unroll
    for (int j = 0; j < 8; ++j) part[g][t * 8 + j] = a[j];
    __syncthreads();
    int c = threadIdx.x;
    float s = 0.f;
#pragma unroll
    for (int g2i = 0; g2i < 8; ++g2i) s += part[g2i][c];
    inc[(size_t)bn * H + c] = (bf16_t)(s * (1.f / 64.f) * ss[c] + ss[256 + c] * (63.f / 64.f));
}

// fc w/ inline BN4 finalize
__global__ void fc_kernel(const bf16_t* __restrict__ x4, const float* __restrict__ stats4,
                          const float* __restrict__ g4, const float* __restrict__ be4,
                          const float* __restrict__ fcw, const float* __restrict__ fcb,
                          float* __restrict__ out)
{
    __shared__ float ss[512];
    {
        int c = threadIdx.x;
        float mean = stats4[c] / (float)M_EDGE;
        float var  = stats4[256 + c] / (float)M_EDGE - mean * mean;
        float scl  = g4[c] * rsqrtf(var + BN_EPS);
        ss[c]       = scl;
        ss[256 + c] = be4[c] - mean * scl;
    }
    __syncthreads();
    int row  = blockIdx.x * 8 + (threadIdx.x >> 5);
    int t    = threadIdx.x & 31;
    bf16x8 v8 = *(const bf16x8*)(x4 + (size_t)row * H + t * 8);
    float s0 = 0.f, s1 = 0.f;
#pragma unroll
    for (int j = 0; j < 8; ++j) {
        int c = t * 8 + j;
        float v = (float)v8[j] * ss[c] + ss[256 + c];
        s0 += v * fcw[c * 2];
        s1 += v * fcw[c * 2 + 1];
    }
#pragma unroll
    for (int off = 16; off; off >>= 1) {
        s0 += __shfl_down(s0, off, 32);
        s1 += __shfl_down(s1, off, 32);
    }
    if (t == 0) {
        out[(size_t)row * 2]     = s0 + fcb[0];
        out[(size_t)row * 2 + 1] = s1 + fcb[1];
    }
}

// ---------------------------------------------------------------------------
extern "C" void kernel_launch(void* const* d_in, const int* in_sizes, int n_in,
                              void* d_out, int out_size, void* d_ws, size_t ws_size,
                              hipStream_t stream)
{
    (void)in_sizes; (void)n_in; (void)out_size; (void)ws_size;
    const float* inp = (const float*)d_in[0];
    const float* w1a = (const float*)d_in[3];  const float* b1a = (const float*)d_in[4];
    const float* w1b = (const float*)d_in[5];  const float* b1b = (const float*)d_in[6];
    const float* g1  = (const float*)d_in[7];  const float* be1 = (const float*)d_in[8];
    const float* w2a = (const float*)d_in[9];  const float* b2a = (const float*)d_in[10];
    const float* w2b = (const float*)d_in[11]; const float* b2b = (const float*)d_in[12];
    const float* g2  = (const float*)d_in[13]; const float* be2 = (const float*)d_in[14];
    const float* w3a = (const float*)d_in[15]; const float* b3a = (const float*)d_in[16];
    const float* w3b = (const float*)d_in[17]; const float* b3b = (const float*)d_in[18];
    const float* g3  = (const float*)d_in[19]; const float* be3 = (const float*)d_in[20];
    const float* w4a = (const float*)d_in[21]; const float* b4a = (const float*)d_in[22];
    const float* w4b = (const float*)d_in[23]; const float* b4b = (const float*)d_in[24];
    const float* g4  = (const float*)d_in[25]; const float* be4 = (const float*)d_in[26];
    const float* fcw = (const float*)d_in[27]; const float* fcb = (const float*)d_in[28];

    char* p = (char*)d_ws;
    auto alloc = [&](size_t nbytes) { char* r = p; p += (nbytes + 255) & ~(size_t)255; return r; };

    bf16_t* wt1a = (bf16_t*)alloc(256 * 256 * 2);
    bf16_t* wt1b = (bf16_t*)alloc(256 * 256 * 2);
    bf16_t* wt2b = (bf16_t*)alloc(256 * 256 * 2);
    bf16_t* wt3a = (bf16_t*)alloc(256 * 256 * 2);
    bf16_t* wt3b = (bf16_t*)alloc(256 * 256 * 2);
    bf16_t* wt4b = (bf16_t*)alloc(256 * 256 * 2);
    bf16_t* wtpq = (bf16_t*)alloc(512 * 256 * 2);
    bf16_t* wtrs = (bf16_t*)alloc(512 * 256 * 2);
    bf16_t* wtsk = (bf16_t*)alloc(256 * 256 * 2);
    float*  biasPQ = (float*)alloc(512 * sizeof(float));
    float*  biasRS = (float*)alloc(512 * sizeof(float));
    float*  stats  = (float*)alloc(4 * 512 * sizeof(float));
    bf16_t* x1   = (bf16_t*)alloc((size_t)M_NODE * H * 2);
    bf16_t* incb = (bf16_t*)alloc((size_t)M_NODE * H * 2);
    bf16_t* x3   = (bf16_t*)alloc((size_t)M_NODE * H * 2);
    bf16_t* PQ   = (bf16_t*)alloc((size_t)M_NODE * 512 * 2);
    float*  RS   = (float*)alloc((size_t)M_NODE * 512 * sizeof(float));
    bf16_t* h2   = (bf16_t*)alloc((size_t)M_EDGE * H * 2);
    bf16_t* h4   = (bf16_t*)alloc((size_t)M_EDGE * H * 2);

    // all static prep in one launch
    prep<<<2562, 256, 0, stream>>>(w1a, wt1a, w1b, wt1b, w2b, wt2b, w3a, wt3a,
                                   w3b, wt3b, w4b, wt4b, w2a, wtpq, w4a, wtrs,
                                   b2a, biasPQ, stats);

    // MLP1 (nodes, streamed B, M-tile 32) -> x1, stats1
    fused_mlp<true ><<<M_NODE / 32, 256, 0, stream>>>(inp, wt1a, b1a, wt1b, b1b, x1, stats + 0);

    // PQ (bf16) = BN1(x1) @ [W2a_s | W2a_r] + [b2a|0]
    { dim3 g(M_NODE / 32, 2);
      node_gemm<true ><<<g, 256, 0, stream>>>(x1, stats + 0, g1, be1, (float)M_NODE, wtpq, biasPQ, PQ); }

    // MLP2 (edges, bf16 PQ gather + streamed B + swizzled LDS) -> h2, stats2
    m2_kernel<<<M_EDGE / 64, 256, 0, stream>>>(PQ, wt2b, b2b, h2, stats + 512);

    // edge2node (BN2 finalize+fold inline) + MLP3 (nodes, streamed B, M-tile 32)
    edge2node<<<M_NODE, 256, 0, stream>>>(h2, stats + 512, g2, be2, incb);
    fused_mlp<false><<<M_NODE / 32, 256, 0, stream>>>(incb, wt3a, b3a, wt3b, b3b, x3, stats + 1024);

    // BN2-folded skip weight (fragment order) + RS bias
    prep2<<<257, 256, 0, stream>>>(w4a, stats + 512, g2, be2, b4a, wtsk, biasRS);
    // RS (f32) = BN3(x3) @ [W4a_s | W4a_r] + biasRS
    { dim3 g(M_NODE / 32, 2);
      node_gemm<false><<<g, 256, 0, stream>>>(x3, stats + 1024, g3, be3, (float)M_NODE, wtrs, biasRS, RS); }

    // MLP4 (edges, streamed B + RS-init-acc + async swizzled stage) -> h4, stats4
    m4_kernel<<<M_EDGE / 64, 256, 0, stream>>>(h2, wtsk, RS, wt4b, b4b, h4, stats + 1536);

    // final fc with BN4 finalize+fold inline, fp32 output
    fc_kernel<<<M_EDGE / 8, 256, 0, stream>>>(h4, stats + 1536, g4, be4, fcw, fcb, (float*)d_out);
}